// Round 2
// baseline (10116.271 us; speedup 1.0000x reference)
//
#include <hip/hip_runtime.h>
#include <hip/hip_bf16.h>

#define BATCH 256
#define INSZ 256
#define HID 1024
#define OUTSZ 128
#define SEQ 150
#define NG 4096  // 4*HID

typedef __attribute__((ext_vector_type(8))) short bf16x8;
typedef __attribute__((ext_vector_type(4))) float f32x4;

#define MFMA(a, b, c) __builtin_amdgcn_mfma_f32_16x16x32_bf16(a, b, c, 0, 0, 0)

static __device__ __forceinline__ float bf2f(ushort u) {
    union { unsigned int i; float f; } v;
    v.i = ((unsigned int)u) << 16;
    return v.f;
}
static __device__ __forceinline__ ushort f2bf(float f) {
    union { float f; unsigned int i; } v;
    v.f = f;
    unsigned int x = v.i;
    return (ushort)((x + 0x7fffu + ((x >> 16) & 1u)) >> 16);
}

// ---------------------------------------------------------------------------
// prep: build gate-permuted split-bf16 W_hh (row 4u+g = W_hh[g*H+u]), fused
// bias, and bf16 W_out. Runs every call (workspace is re-poisoned).
// ---------------------------------------------------------------------------
__global__ __launch_bounds__(256) void prep_kernel(
    const float* __restrict__ Whh, const float* __restrict__ b_ih,
    const float* __restrict__ b_hh, const float* __restrict__ Wout,
    ushort* __restrict__ Whi, ushort* __restrict__ Wlo,
    ushort* __restrict__ WoutB, float* __restrict__ biasp)
{
    int bid = blockIdx.x, tid = threadIdx.x;
    if (bid < NG) {
        int u = bid >> 2, g = bid & 3;
        const float* src = Whh + (size_t)(g * HID + u) * HID;
        ushort* dhi = Whi + (size_t)bid * HID;
        ushort* dlo = Wlo + (size_t)bid * HID;
#pragma unroll
        for (int i = 0; i < 4; ++i) {
            int k = tid + 256 * i;
            float w = src[k];
            ushort hi = f2bf(w);
            dhi[k] = hi;
            dlo[k] = f2bf(w - bf2f(hi));
        }
        if (tid == 0) biasp[bid] = b_ih[g * HID + u] + b_hh[g * HID + u];
    } else {
        int r = bid - NG;
#pragma unroll
        for (int i = 0; i < 4; ++i) {
            int k = tid + 256 * i;
            WoutB[(size_t)r * HID + k] = f2bf(Wout[(size_t)r * HID + k]);
        }
    }
}

// ---------------------------------------------------------------------------
// init: h0 = x@W_in_h^T + b_in_h (split to bf16 hi/lo), c0 = x@W_in_c^T + b_in_c
// grid: 256 blocks = 64 unit-tiles(16) x 4 batch-tiles(64); 256 threads.
// ---------------------------------------------------------------------------
__global__ __launch_bounds__(256) void init_kernel(
    const float* __restrict__ inp, const float* __restrict__ Wh,
    const float* __restrict__ bh, const float* __restrict__ Wc,
    const float* __restrict__ bc,
    ushort* __restrict__ h_hi, ushort* __restrict__ h_lo, float* __restrict__ c)
{
    __shared__ float xs[64][128];  // 32KB
    int bid = blockIdx.x, tid = threadIdx.x;
    int ut = bid >> 2, bt = bid & 3;
    int U0 = ut * 16, b0 = bt * 64;
    float ah[4], ac[4];
#pragma unroll
    for (int j = 0; j < 4; ++j) {
        int p = tid + 256 * j;
        int U = U0 + (p & 15);
        ah[j] = bh[U];
        ac[j] = bc[U];
    }
    for (int kh = 0; kh < 2; ++kh) {
        __syncthreads();
        for (int i = tid; i < 64 * 128; i += 256)
            xs[i >> 7][i & 127] = inp[(size_t)(b0 + (i >> 7)) * INSZ + kh * 128 + (i & 127)];
        __syncthreads();
#pragma unroll
        for (int j = 0; j < 4; ++j) {
            int p = tid + 256 * j;
            int bl = p >> 4, ul = p & 15;
            int U = U0 + ul;
            const float* wh = Wh + (size_t)U * INSZ + kh * 128;
            const float* wc = Wc + (size_t)U * INSZ + kh * 128;
            float sh = 0.f, sc = 0.f;
            for (int k = 0; k < 128; ++k) {
                float x = xs[bl][k];
                sh += x * wh[k];
                sc += x * wc[k];
            }
            ah[j] += sh;
            ac[j] += sc;
        }
    }
#pragma unroll
    for (int j = 0; j < 4; ++j) {
        int p = tid + 256 * j;
        int bl = p >> 4, ul = p & 15;
        int gi = (b0 + bl) * HID + U0 + ul;
        ushort hh = f2bf(ah[j]);
        h_hi[gi] = hh;
        h_lo[gi] = f2bf(ah[j] - bf2f(hh));
        c[gi] = ac[j];
    }
}

// ---------------------------------------------------------------------------
// step: fused gates GEMM (split-bf16, virtual K = 3x1024) + activations +
// c/h update + h re-split + lstm_out store.
// grid: 256 WGs = 4 batch-tiles(64) x 64 gate-tiles(64); 512 threads (8 waves,
// 2Mx4N of 32x16 each). Fragments loaded straight from global (L2-hot).
// ---------------------------------------------------------------------------
__global__ __launch_bounds__(512) void step_kernel(
    const ushort* __restrict__ hin_hi, const ushort* __restrict__ hin_lo,
    float* __restrict__ c,
    ushort* __restrict__ hout_hi, ushort* __restrict__ hout_lo,
    ushort* __restrict__ lstm_t,  // base + t*HID, row stride SEQ*HID
    const ushort* __restrict__ Whi, const ushort* __restrict__ Wlo,
    const float* __restrict__ biasp)
{
    __shared__ float gl[64][65];
    int tid = threadIdx.x;
    int wave = tid >> 6, lane = tid & 63;
    int wm = wave >> 2, wn = wave & 3;
    int ntile = blockIdx.x & 63, mtile = blockIdx.x >> 6;
    int N0 = ntile * 64, b0 = mtile * 64;
    int l15 = lane & 15, lk = (lane >> 4) * 8;

    f32x4 acc0 = {}, acc1 = {};
    int row0 = b0 + wm * 32 + l15;
    int colj = N0 + wn * 16 + l15;

    for (int pass = 0; pass < 3; ++pass) {
        const ushort* Ap = (pass == 1) ? hin_lo : hin_hi;
        const ushort* Bp = (pass == 2) ? Wlo : Whi;
        const ushort* a0p = Ap + (size_t)row0 * HID + lk;
        const ushort* a1p = a0p + 16 * HID;
        const ushort* bp = Bp + (size_t)colj * HID + lk;
#pragma unroll 8
        for (int k0 = 0; k0 < 32; ++k0) {
            bf16x8 a0 = *(const bf16x8*)(a0p + k0 * 32);
            bf16x8 a1 = *(const bf16x8*)(a1p + k0 * 32);
            bf16x8 bb = *(const bf16x8*)(bp + k0 * 32);
            acc0 = MFMA(a0, bb, acc0);
            acc1 = MFMA(a1, bb, acc1);
        }
    }

    // dump gate tile to LDS for quad regrouping
    int cl = wn * 16 + l15;
    int rbase = wm * 32 + (lane >> 4) * 4;
#pragma unroll
    for (int r = 0; r < 4; ++r) {
        gl[rbase + r][cl] = acc0[r];
        gl[rbase + 16 + r][cl] = acc1[r];
    }
    __syncthreads();

#pragma unroll
    for (int pp = 0; pp < 2; ++pp) {
        int p = tid + 512 * pp;
        int bl = p >> 4, ul = p & 15;
        int jb = N0 + ul * 4;
        float xi = gl[bl][ul * 4 + 0] + biasp[jb + 0];
        float xf = gl[bl][ul * 4 + 1] + biasp[jb + 1];
        float xg = gl[bl][ul * 4 + 2] + biasp[jb + 2];
        float xo = gl[bl][ul * 4 + 3] + biasp[jb + 3];
        float ig = 1.f / (1.f + __expf(-xi));
        float fg = 1.f / (1.f + __expf(-xf));
        float xgc = fminf(fmaxf(xg, -30.f), 30.f);
        float eg = __expf(-2.f * xgc);
        float gg = (1.f - eg) / (1.f + eg);
        float og = 1.f / (1.f + __expf(-xo));
        int gidx = (b0 + bl) * HID + (N0 >> 2) + ul;
        float cn = fg * c[gidx] + ig * gg;
        float cc = fminf(fmaxf(cn, -30.f), 30.f);
        float ec = __expf(-2.f * cc);
        float th = (1.f - ec) / (1.f + ec);
        float h = og * th;
        c[gidx] = cn;
        ushort hh = f2bf(h);
        hout_hi[gidx] = hh;
        hout_lo[gidx] = f2bf(h - bf2f(hh));
        lstm_t[(size_t)(b0 + bl) * (SEQ * HID) + (N0 >> 2) + ul] = hh;
    }
}

// ---------------------------------------------------------------------------
// final: predictions[38400,128] = lstm_bf16 @ WoutB^T + b_out
// grid: 600 blocks x 512 threads (8 waves, 2Mx4N of 32x32).
// ---------------------------------------------------------------------------
__global__ __launch_bounds__(512) void final_kernel(
    const ushort* __restrict__ lstm, const ushort* __restrict__ WoutB,
    const float* __restrict__ b_out, float* __restrict__ out)
{
    int tid = threadIdx.x;
    int wave = tid >> 6, lane = tid & 63;
    int wm = wave >> 2, wn = wave & 3;
    int m0 = blockIdx.x * 64;
    int l15 = lane & 15, lk = (lane >> 4) * 8;
    int r0 = m0 + wm * 32 + l15;
    int j0 = wn * 32 + l15;
    f32x4 acc00 = {}, acc01 = {}, acc10 = {}, acc11 = {};
    const ushort* a0p = lstm + (size_t)r0 * HID + lk;
    const ushort* a1p = a0p + (size_t)16 * HID;
    const ushort* bp0 = WoutB + (size_t)j0 * HID + lk;
    const ushort* bp1 = bp0 + (size_t)16 * HID;
#pragma unroll 4
    for (int k0 = 0; k0 < 32; ++k0) {
        bf16x8 a0 = *(const bf16x8*)(a0p + k0 * 32);
        bf16x8 a1 = *(const bf16x8*)(a1p + k0 * 32);
        bf16x8 bb0 = *(const bf16x8*)(bp0 + k0 * 32);
        bf16x8 bb1 = *(const bf16x8*)(bp1 + k0 * 32);
        acc00 = MFMA(a0, bb0, acc00);
        acc01 = MFMA(a0, bb1, acc01);
        acc10 = MFMA(a1, bb0, acc10);
        acc11 = MFMA(a1, bb1, acc11);
    }
#pragma unroll
    for (int r = 0; r < 4; ++r) {
        int rA = m0 + wm * 32 + (lane >> 4) * 4 + r;
        int rB = rA + 16;
        int c0 = wn * 32 + l15;
        int c1 = c0 + 16;
        out[(size_t)rA * OUTSZ + c0] = acc00[r] + b_out[c0];
        out[(size_t)rA * OUTSZ + c1] = acc01[r] + b_out[c1];
        out[(size_t)rB * OUTSZ + c0] = acc10[r] + b_out[c0];
        out[(size_t)rB * OUTSZ + c1] = acc11[r] + b_out[c1];
    }
}

// ---------------------------------------------------------------------------
extern "C" void kernel_launch(void* const* d_in, const int* in_sizes, int n_in,
                              void* d_out, int out_size, void* d_ws, size_t ws_size,
                              hipStream_t stream)
{
    const float* init_input = (const float*)d_in[0];
    const float* W_in_h = (const float*)d_in[1];
    const float* b_in_h = (const float*)d_in[2];
    const float* W_in_c = (const float*)d_in[3];
    const float* b_in_c = (const float*)d_in[4];
    const float* W_hh = (const float*)d_in[5];
    const float* b_ih = (const float*)d_in[6];
    const float* b_hh = (const float*)d_in[7];
    const float* W_out = (const float*)d_in[8];
    const float* b_out = (const float*)d_in[9];
    float* out = (float*)d_out;

    char* ws = (char*)d_ws;
    ushort* Whi = (ushort*)(ws);                    // 8 MB
    ushort* Wlo = (ushort*)(ws + 8388608);          // 8 MB
    ushort* WoutB = (ushort*)(ws + 16777216);       // 256 KB
    float* biasp = (float*)(ws + 17039360);         // 16 KB
    ushort* hA_hi = (ushort*)(ws + 17055744);       // 512 KB
    ushort* hA_lo = (ushort*)(ws + 17580032);       // 512 KB
    ushort* hB_hi = (ushort*)(ws + 18104320);       // 512 KB
    ushort* hB_lo = (ushort*)(ws + 18628608);       // 512 KB
    float* cbuf = (float*)(ws + 19152896);          // 1 MB
    ushort* lstm = (ushort*)(ws + 20201472);        // 78.6 MB -> total ~94.3 MB

    hipLaunchKernelGGL(prep_kernel, dim3(4224), dim3(256), 0, stream,
                       W_hh, b_ih, b_hh, W_out, Whi, Wlo, WoutB, biasp);
    hipLaunchKernelGGL(init_kernel, dim3(256), dim3(256), 0, stream,
                       init_input, W_in_h, b_in_h, W_in_c, b_in_c,
                       hA_hi, hA_lo, cbuf);
    for (int t = 0; t < SEQ; ++t) {
        const ushort* ih = (t & 1) ? hB_hi : hA_hi;
        const ushort* il = (t & 1) ? hB_lo : hA_lo;
        ushort* oh = (t & 1) ? hA_hi : hB_hi;
        ushort* ol = (t & 1) ? hA_lo : hB_lo;
        hipLaunchKernelGGL(step_kernel, dim3(256), dim3(512), 0, stream,
                           ih, il, cbuf, oh, ol, lstm + (size_t)t * HID,
                           Whi, Wlo, biasp);
    }
    hipLaunchKernelGGL(final_kernel, dim3(600), dim3(512), 0, stream,
                       lstm, WoutB, b_out, out);
}

// Round 6
// 7459.393 us; speedup vs baseline: 1.3562x; 1.3562x over previous
//
#include <hip/hip_runtime.h>
#include <hip/hip_bf16.h>
#include <hip/hip_cooperative_groups.h>

namespace cg = cooperative_groups;

#define BATCH 256
#define INSZ 256
#define HID 1024
#define OUTSZ 128
#define SEQ 150
#define NG 4096  // 4*HID

typedef __attribute__((ext_vector_type(8))) short bf16x8;
typedef __attribute__((ext_vector_type(4))) float f32x4;

#define MFMA(a, b, c) __builtin_amdgcn_mfma_f32_16x16x32_bf16(a, b, c, 0, 0, 0)

static __device__ __forceinline__ float bf2f(ushort u) {
    union { unsigned int i; float f; } v;
    v.i = ((unsigned int)u) << 16;
    return v.f;
}
static __device__ __forceinline__ ushort f2bf(float f) {
    union { float f; unsigned int i; } v;
    v.f = f;
    unsigned int x = v.i;
    return (ushort)((x + 0x7fffu + ((x >> 16) & 1u)) >> 16);
}

// ---------------------------------------------------------------------------
// prep: build gate-permuted split-bf16 W_hh (row 4u+g = W_hh[g*H+u]), fused
// bias, and bf16 W_out. (Also feeds the fallback path.)
// ---------------------------------------------------------------------------
__global__ __launch_bounds__(256) void prep_kernel(
    const float* __restrict__ Whh, const float* __restrict__ b_ih,
    const float* __restrict__ b_hh, const float* __restrict__ Wout,
    ushort* __restrict__ Whi, ushort* __restrict__ Wlo,
    ushort* __restrict__ WoutB, float* __restrict__ biasp)
{
    int bid = blockIdx.x, tid = threadIdx.x;
    if (bid < NG) {
        int u = bid >> 2, g = bid & 3;
        const float* src = Whh + (size_t)(g * HID + u) * HID;
        ushort* dhi = Whi + (size_t)bid * HID;
        ushort* dlo = Wlo + (size_t)bid * HID;
#pragma unroll
        for (int i = 0; i < 4; ++i) {
            int k = tid + 256 * i;
            float w = src[k];
            ushort hi = f2bf(w);
            dhi[k] = hi;
            dlo[k] = f2bf(w - bf2f(hi));
        }
        if (tid == 0) biasp[bid] = b_ih[g * HID + u] + b_hh[g * HID + u];
    } else {
        int r = bid - NG;
#pragma unroll
        for (int i = 0; i < 4; ++i) {
            int k = tid + 256 * i;
            WoutB[(size_t)r * HID + k] = f2bf(Wout[(size_t)r * HID + k]);
        }
    }
}

// ---------------------------------------------------------------------------
// init: h0 = x@W_in_h^T + b_in_h (split to bf16 hi/lo), c0 = x@W_in_c^T + b_in_c
// ---------------------------------------------------------------------------
__global__ __launch_bounds__(256) void init_kernel(
    const float* __restrict__ inp, const float* __restrict__ Wh,
    const float* __restrict__ bh, const float* __restrict__ Wc,
    const float* __restrict__ bc,
    ushort* __restrict__ h_hi, ushort* __restrict__ h_lo, float* __restrict__ c)
{
    __shared__ float xs[64][128];  // 32KB
    int bid = blockIdx.x, tid = threadIdx.x;
    int ut = bid >> 2, bt = bid & 3;
    int U0 = ut * 16, b0 = bt * 64;
    float ah[4], ac[4];
#pragma unroll
    for (int j = 0; j < 4; ++j) {
        int p = tid + 256 * j;
        int U = U0 + (p & 15);
        ah[j] = bh[U];
        ac[j] = bc[U];
    }
    for (int kh = 0; kh < 2; ++kh) {
        __syncthreads();
        for (int i = tid; i < 64 * 128; i += 256)
            xs[i >> 7][i & 127] = inp[(size_t)(b0 + (i >> 7)) * INSZ + kh * 128 + (i & 127)];
        __syncthreads();
#pragma unroll
        for (int j = 0; j < 4; ++j) {
            int p = tid + 256 * j;
            int bl = p >> 4, ul = p & 15;
            int U = U0 + ul;
            const float* wh = Wh + (size_t)U * INSZ + kh * 128;
            const float* wc = Wc + (size_t)U * INSZ + kh * 128;
            float sh = 0.f, sc = 0.f;
            for (int k = 0; k < 128; ++k) {
                float x = xs[bl][k];
                sh += x * wh[k];
                sc += x * wc[k];
            }
            ah[j] += sh;
            ac[j] += sc;
        }
    }
#pragma unroll
    for (int j = 0; j < 4; ++j) {
        int p = tid + 256 * j;
        int bl = p >> 4, ul = p & 15;
        int gi = (b0 + bl) * HID + U0 + ul;
        ushort hh = f2bf(ah[j]);
        h_hi[gi] = hh;
        h_lo[gi] = f2bf(ah[j] - bf2f(hh));
        c[gi] = ac[j];
    }
}

// ---------------------------------------------------------------------------
// persist: cooperative persistent LSTM. 256 blocks (1/CU), 512 thr (8 waves).
// Block (ct,hf) owns output tile (batch rows hf*128..+128, gate cols ct*32..+32).
// Weights (hi+lo, 128KB) stay in swizzled LDS for all 150 steps; c stays in
// registers; h double-buffers through global; grid.sync() per step.
// Wave w = rows w*16..+16 (no A duplication); per wave 2 col-frags.
// ---------------------------------------------------------------------------
#define PERSIST_LDS (131072 + 128 * 36 * 4)  // Whi 64K + Wlo 64K + gl 18K

__global__ __launch_bounds__(512, 2) void persist_kernel(
    const ushort* __restrict__ Whi, const ushort* __restrict__ Wlo,
    const float* __restrict__ biasp, const float* __restrict__ c0,
    ushort* __restrict__ h0hi, ushort* __restrict__ h0lo,
    ushort* __restrict__ h1hi, ushort* __restrict__ h1lo,
    ushort* __restrict__ lstm)
{
    extern __shared__ char smem[];
    float* gl = (float*)(smem + 131072);  // [128][36] floats

    cg::grid_group grid = cg::this_grid();

    int tid = threadIdx.x;
    int bid = blockIdx.x;
    int ct = bid >> 1;   // col tile 0..127 (32 gate cols each)
    int hf = bid & 1;    // batch half
    int wave = tid >> 6, lane = tid & 63;
    int l15 = lane & 15, lk = (lane >> 4) * 8;

    // ---- stage weights into LDS (once), swizzled within each col's 2KB ----
    {
        const ushort* srcH = Whi + (size_t)ct * 32768;
        const ushort* srcL = Wlo + (size_t)ct * 32768;
#pragma unroll
        for (int i = 0; i < 8; ++i) {
            int o = (tid + i * 512) * 8;          // ushort idx in 32x1024
            int j = o >> 10;                      // col 0..31
            int kb = (o & 1023) * 2;              // byte in col, 16B-aligned
            int dst = (j * 2048 + kb) ^ ((j & 7) << 4);
            *(bf16x8*)(smem + dst) = *(const bf16x8*)(srcH + o);
            *(bf16x8*)(smem + 65536 + dst) = *(const bf16x8*)(srcL + o);
        }
    }
    // bias regs (fixed cols all steps)
    float bias0 = biasp[ct * 32 + l15];
    float bias1 = biasp[ct * 32 + 16 + l15];
    // c in registers: epilogue mapping p = tid + 512*pp -> (row=p>>3, unit=p&7)
    float creg[2];
    int erow0 = tid >> 3, eu0 = tid & 7;
    int erow1 = (tid + 512) >> 3, eu1 = tid & 7;
    creg[0] = c0[(size_t)(hf * 128 + erow0) * HID + ct * 8 + eu0];
    creg[1] = c0[(size_t)(hf * 128 + erow1) * HID + ct * 8 + eu1];
    __syncthreads();

    int r0 = hf * 128 + wave * 16 + l15;       // A-frag batch row
    const size_t arow = (size_t)r0 * HID + lk;
    // per-lane LDS B-frag swizzle constants
    int sw = (l15 & 7) << 4;
    int cbase0 = l15 * 2048;
    int cbase1 = (16 + l15) * 2048;
    int qbase = lk * 2;

    for (int t = 0; t < SEQ; ++t) {
        const ushort* hH = (t & 1) ? h1hi : h0hi;
        const ushort* hL = (t & 1) ? h1lo : h0lo;
        ushort* oH = (t & 1) ? h0hi : h1hi;
        ushort* oL = (t & 1) ? h0lo : h1lo;

        f32x4 acc0 = {}, acc1 = {};
        const ushort* ah = hH + arow;
        const ushort* al = hL + arow;
#pragma unroll 4
        for (int kk = 0; kk < 32; ++kk) {
            int q = (qbase + kk * 64) ^ sw;
            bf16x8 ahi = *(const bf16x8*)(ah + kk * 32);
            bf16x8 alo = *(const bf16x8*)(al + kk * 32);
            bf16x8 bh0 = *(const bf16x8*)(smem + cbase0 + q);
            bf16x8 bh1 = *(const bf16x8*)(smem + cbase1 + q);
            bf16x8 bl0 = *(const bf16x8*)(smem + 65536 + cbase0 + q);
            bf16x8 bl1 = *(const bf16x8*)(smem + 65536 + cbase1 + q);
            acc0 = MFMA(ahi, bh0, acc0);
            acc1 = MFMA(ahi, bh1, acc1);
            acc0 = MFMA(alo, bh0, acc0);
            acc1 = MFMA(alo, bh1, acc1);
            acc0 = MFMA(ahi, bl0, acc0);
            acc1 = MFMA(ahi, bl1, acc1);
        }

        // ---- dump biased gates to LDS for quad regroup ----
        int drow = wave * 16 + (lane >> 4) * 4;
#pragma unroll
        for (int r = 0; r < 4; ++r) {
            gl[(drow + r) * 36 + l15] = acc0[r] + bias0;
            gl[(drow + r) * 36 + 16 + l15] = acc1[r] + bias1;
        }
        __syncthreads();

        ushort* lst = lstm + (size_t)t * HID;
#pragma unroll
        for (int pp = 0; pp < 2; ++pp) {
            int row = pp ? erow1 : erow0;
            int ul = pp ? eu1 : eu0;
            float4 q4 = *(const float4*)((const char*)gl + row * 144 + ul * 16);
            float xi = q4.x, xf = q4.y, xg = q4.z, xo = q4.w;
            float ig = 1.f / (1.f + __expf(-xi));
            float fg = 1.f / (1.f + __expf(-xf));
            float xgc = fminf(fmaxf(xg, -30.f), 30.f);
            float eg = __expf(-2.f * xgc);
            float gg = (1.f - eg) / (1.f + eg);
            float og = 1.f / (1.f + __expf(-xo));
            float cn = fg * creg[pp] + ig * gg;
            creg[pp] = cn;
            float cc = fminf(fmaxf(cn, -30.f), 30.f);
            float ec = __expf(-2.f * cc);
            float th = (1.f - ec) / (1.f + ec);
            float h = og * th;
            int grow = hf * 128 + row;
            size_t gi = (size_t)grow * HID + ct * 8 + ul;
            ushort hh = f2bf(h);
            oH[gi] = hh;
            oL[gi] = f2bf(h - bf2f(hh));
            lst[(size_t)grow * (SEQ * HID) + ct * 8 + ul] = hh;
        }
        if (t < SEQ - 1) grid.sync();
    }
}

// ---------------------------------------------------------------------------
// step (FALLBACK ONLY, proven-correct round-2 path)
// ---------------------------------------------------------------------------
__global__ __launch_bounds__(512) void step_kernel(
    const ushort* __restrict__ hin_hi, const ushort* __restrict__ hin_lo,
    float* __restrict__ c,
    ushort* __restrict__ hout_hi, ushort* __restrict__ hout_lo,
    ushort* __restrict__ lstm_t,
    const ushort* __restrict__ Whi, const ushort* __restrict__ Wlo,
    const float* __restrict__ biasp)
{
    __shared__ float gl[64][65];
    int tid = threadIdx.x;
    int wave = tid >> 6, lane = tid & 63;
    int wm = wave >> 2, wn = wave & 3;
    int ntile = blockIdx.x & 63, mtile = blockIdx.x >> 6;
    int N0 = ntile * 64, b0 = mtile * 64;
    int l15 = lane & 15, lk = (lane >> 4) * 8;

    f32x4 acc0 = {}, acc1 = {};
    int row0 = b0 + wm * 32 + l15;
    int colj = N0 + wn * 16 + l15;

    for (int pass = 0; pass < 3; ++pass) {
        const ushort* Ap = (pass == 1) ? hin_lo : hin_hi;
        const ushort* Bp = (pass == 2) ? Wlo : Whi;
        const ushort* a0p = Ap + (size_t)row0 * HID + lk;
        const ushort* a1p = a0p + 16 * HID;
        const ushort* bp = Bp + (size_t)colj * HID + lk;
#pragma unroll 8
        for (int k0 = 0; k0 < 32; ++k0) {
            bf16x8 a0 = *(const bf16x8*)(a0p + k0 * 32);
            bf16x8 a1 = *(const bf16x8*)(a1p + k0 * 32);
            bf16x8 bb = *(const bf16x8*)(bp + k0 * 32);
            acc0 = MFMA(a0, bb, acc0);
            acc1 = MFMA(a1, bb, acc1);
        }
    }
    int cl = wn * 16 + l15;
    int rbase = wm * 32 + (lane >> 4) * 4;
#pragma unroll
    for (int r = 0; r < 4; ++r) {
        gl[rbase + r][cl] = acc0[r];
        gl[rbase + 16 + r][cl] = acc1[r];
    }
    __syncthreads();
#pragma unroll
    for (int pp = 0; pp < 2; ++pp) {
        int p = tid + 512 * pp;
        int bl = p >> 4, ul = p & 15;
        int jb = N0 + ul * 4;
        float xi = gl[bl][ul * 4 + 0] + biasp[jb + 0];
        float xf = gl[bl][ul * 4 + 1] + biasp[jb + 1];
        float xg = gl[bl][ul * 4 + 2] + biasp[jb + 2];
        float xo = gl[bl][ul * 4 + 3] + biasp[jb + 3];
        float ig = 1.f / (1.f + __expf(-xi));
        float fg = 1.f / (1.f + __expf(-xf));
        float xgc = fminf(fmaxf(xg, -30.f), 30.f);
        float eg = __expf(-2.f * xgc);
        float gg = (1.f - eg) / (1.f + eg);
        float og = 1.f / (1.f + __expf(-xo));
        int gidx = (b0 + bl) * HID + (N0 >> 2) + ul;
        float cn = fg * c[gidx] + ig * gg;
        float cc = fminf(fmaxf(cn, -30.f), 30.f);
        float ec = __expf(-2.f * cc);
        float th = (1.f - ec) / (1.f + ec);
        float h = og * th;
        c[gidx] = cn;
        ushort hh = f2bf(h);
        hout_hi[gidx] = hh;
        hout_lo[gidx] = f2bf(h - bf2f(hh));
        lstm_t[(size_t)(b0 + bl) * (SEQ * HID) + (N0 >> 2) + ul] = hh;
    }
}

// ---------------------------------------------------------------------------
// final: predictions[38400,128] = lstm_bf16 @ WoutB^T + b_out
// 1200 blocks x 512 thr (8 waves = 2 row x 4 col), 32-row tiles for TLP.
// ---------------------------------------------------------------------------
__global__ __launch_bounds__(512) void final_kernel(
    const ushort* __restrict__ lstm, const ushort* __restrict__ WoutB,
    const float* __restrict__ b_out, float* __restrict__ out)
{
    int tid = threadIdx.x;
    int wave = tid >> 6, lane = tid & 63;
    int wr = wave >> 2, wc = wave & 3;
    int m0 = blockIdx.x * 32;
    int l15 = lane & 15, lk = (lane >> 4) * 8;
    int r0 = m0 + wr * 16 + l15;
    int j0 = wc * 32 + l15;
    f32x4 acc0 = {}, acc1 = {};
    const ushort* ap = lstm + (size_t)r0 * HID + lk;
    const ushort* bp0 = WoutB + (size_t)j0 * HID + lk;
    const ushort* bp1 = bp0 + (size_t)16 * HID;
#pragma unroll 8
    for (int k0 = 0; k0 < 32; ++k0) {
        bf16x8 a = *(const bf16x8*)(ap + k0 * 32);
        bf16x8 b0 = *(const bf16x8*)(bp0 + k0 * 32);
        bf16x8 b1 = *(const bf16x8*)(bp1 + k0 * 32);
        acc0 = MFMA(a, b0, acc0);
        acc1 = MFMA(a, b1, acc1);
    }
#pragma unroll
    for (int r = 0; r < 4; ++r) {
        int rA = m0 + wr * 16 + (lane >> 4) * 4 + r;
        int c0 = wc * 32 + l15, c1 = c0 + 16;
        out[(size_t)rA * OUTSZ + c0] = acc0[r] + b_out[c0];
        out[(size_t)rA * OUTSZ + c1] = acc1[r] + b_out[c1];
    }
}

// ---------------------------------------------------------------------------
extern "C" void kernel_launch(void* const* d_in, const int* in_sizes, int n_in,
                              void* d_out, int out_size, void* d_ws, size_t ws_size,
                              hipStream_t stream)
{
    const float* init_input = (const float*)d_in[0];
    const float* W_in_h = (const float*)d_in[1];
    const float* b_in_h = (const float*)d_in[2];
    const float* W_in_c = (const float*)d_in[3];
    const float* b_in_c = (const float*)d_in[4];
    const float* W_hh = (const float*)d_in[5];
    const float* b_ih = (const float*)d_in[6];
    const float* b_hh = (const float*)d_in[7];
    const float* W_out = (const float*)d_in[8];
    const float* b_out = (const float*)d_in[9];
    float* out = (float*)d_out;

    char* ws = (char*)d_ws;
    ushort* Whi = (ushort*)(ws);                    // 8 MB
    ushort* Wlo = (ushort*)(ws + 8388608);          // 8 MB
    ushort* WoutB = (ushort*)(ws + 16777216);       // 256 KB
    float* biasp = (float*)(ws + 17039360);         // 16 KB
    ushort* hA_hi = (ushort*)(ws + 17055744);       // 512 KB
    ushort* hA_lo = (ushort*)(ws + 17580032);       // 512 KB
    ushort* hB_hi = (ushort*)(ws + 18104320);       // 512 KB
    ushort* hB_lo = (ushort*)(ws + 18628608);       // 512 KB
    float* cbuf = (float*)(ws + 19152896);          // 1 MB
    ushort* lstm = (ushort*)(ws + 20201472);        // 78.6 MB

    hipLaunchKernelGGL(prep_kernel, dim3(4224), dim3(256), 0, stream,
                       W_hh, b_ih, b_hh, W_out, Whi, Wlo, WoutB, biasp);
    hipLaunchKernelGGL(init_kernel, dim3(256), dim3(256), 0, stream,
                       init_input, W_in_h, b_in_h, W_in_c, b_in_c,
                       hA_hi, hA_lo, cbuf);

    // persistent cooperative path
    hipFuncSetAttribute((const void*)persist_kernel,
                        hipFuncAttributeMaxDynamicSharedMemorySize, PERSIST_LDS);
    const ushort* a0 = Whi; const ushort* a1 = Wlo;
    const float* a2 = biasp; const float* a3 = cbuf;
    ushort* a4 = hA_hi; ushort* a5 = hA_lo;
    ushort* a6 = hB_hi; ushort* a7 = hB_lo;
    ushort* a8 = lstm;
    void* kargs[] = {(void*)&a0, (void*)&a1, (void*)&a2, (void*)&a3,
                     (void*)&a4, (void*)&a5, (void*)&a6, (void*)&a7, (void*)&a8};
    hipError_t e = hipLaunchCooperativeKernel((void*)persist_kernel,
                                              dim3(256), dim3(512), kargs,
                                              PERSIST_LDS, stream);
    if (e != hipSuccess) {
        // fallback: proven per-step launch path
        for (int t = 0; t < SEQ; ++t) {
            const ushort* ih = (t & 1) ? hB_hi : hA_hi;
            const ushort* il = (t & 1) ? hB_lo : hA_lo;
            ushort* oh = (t & 1) ? hA_hi : hB_hi;
            ushort* ol = (t & 1) ? hA_lo : hB_lo;
            hipLaunchKernelGGL(step_kernel, dim3(256), dim3(512), 0, stream,
                               ih, il, cbuf, oh, ol, lstm + (size_t)t * HID,
                               Whi, Wlo, biasp);
        }
    }
    hipLaunchKernelGGL(final_kernel, dim3(1200), dim3(512), 0, stream,
                       lstm, WoutB, b_out, out);
}

// Round 7
// 5516.220 us; speedup vs baseline: 1.8339x; 1.3523x over previous
//
#include <hip/hip_runtime.h>
#include <hip/hip_bf16.h>

#define BATCH 256
#define INSZ 256
#define HID 1024
#define OUTSZ 128
#define SEQ 150
#define NG 4096  // 4*HID

typedef __attribute__((ext_vector_type(8))) short bf16x8;
typedef __attribute__((ext_vector_type(4))) float f32x4;

#define MFMA(a, b, c) __builtin_amdgcn_mfma_f32_16x16x32_bf16(a, b, c, 0, 0, 0)

static __device__ __forceinline__ float bf2f(ushort u) {
    union { unsigned int i; float f; } v;
    v.i = ((unsigned int)u) << 16;
    return v.f;
}
static __device__ __forceinline__ ushort f2bf(float f) {
    union { float f; unsigned int i; } v;
    v.f = f;
    unsigned int x = v.i;
    return (ushort)((x + 0x7fffu + ((x >> 16) & 1u)) >> 16);
}

// ---------------------------------------------------------------------------
// Two-level device-scope grid barrier (replaces cg::grid.sync()'s single
// contended counter: 256 RMWs on one line ~= 25-50us/step, measured r6).
// Layout in `bar` (uints, zeroed per launch): [g*16] g=0..15 group counters
// (64B apart), [512] root counter, [544] release flag. Monotonic targets per
// step t: group -> 16(t+1), root -> 16(t+1); no reset needed.
// ---------------------------------------------------------------------------
static __device__ __forceinline__ void gbar(unsigned* bar, int bid, int t) {
    __syncthreads();  // drains vmcnt(0): all block's h stores are in L2
    if (threadIdx.x == 0) {
        __threadfence();  // release: write back dirty L2 (device scope)
        int g = bid >> 4;
        unsigned tgt = (unsigned)(16 * (t + 1));
        unsigned a = __hip_atomic_fetch_add(&bar[g * 16], 1u,
                                            __ATOMIC_RELAXED, __HIP_MEMORY_SCOPE_AGENT);
        if (a == tgt - 1u) {
            unsigned r = __hip_atomic_fetch_add(&bar[512], 1u,
                                                __ATOMIC_RELAXED, __HIP_MEMORY_SCOPE_AGENT);
            if (r == tgt - 1u) {
                __hip_atomic_store(&bar[544], (unsigned)(t + 1),
                                   __ATOMIC_RELEASE, __HIP_MEMORY_SCOPE_AGENT);
            }
        }
        while (__hip_atomic_load(&bar[544], __ATOMIC_ACQUIRE,
                                 __HIP_MEMORY_SCOPE_AGENT) < (unsigned)(t + 1)) {
            __builtin_amdgcn_s_sleep(8);
        }
        __threadfence();  // acquire: invalidate L1/L2 so h reads are fresh
    }
    __syncthreads();
}

// ---------------------------------------------------------------------------
// prep: build gate-permuted split-bf16 W_hh (row 4u+g = W_hh[g*H+u]), fused
// bias, and bf16 W_out. (Also feeds the fallback path.)
// ---------------------------------------------------------------------------
__global__ __launch_bounds__(256) void prep_kernel(
    const float* __restrict__ Whh, const float* __restrict__ b_ih,
    const float* __restrict__ b_hh, const float* __restrict__ Wout,
    ushort* __restrict__ Whi, ushort* __restrict__ Wlo,
    ushort* __restrict__ WoutB, float* __restrict__ biasp)
{
    int bid = blockIdx.x, tid = threadIdx.x;
    if (bid < NG) {
        int u = bid >> 2, g = bid & 3;
        const float* src = Whh + (size_t)(g * HID + u) * HID;
        ushort* dhi = Whi + (size_t)bid * HID;
        ushort* dlo = Wlo + (size_t)bid * HID;
#pragma unroll
        for (int i = 0; i < 4; ++i) {
            int k = tid + 256 * i;
            float w = src[k];
            ushort hi = f2bf(w);
            dhi[k] = hi;
            dlo[k] = f2bf(w - bf2f(hi));
        }
        if (tid == 0) biasp[bid] = b_ih[g * HID + u] + b_hh[g * HID + u];
    } else {
        int r = bid - NG;
#pragma unroll
        for (int i = 0; i < 4; ++i) {
            int k = tid + 256 * i;
            WoutB[(size_t)r * HID + k] = f2bf(Wout[(size_t)r * HID + k]);
        }
    }
}

// ---------------------------------------------------------------------------
// init: h0 = x@W_in_h^T + b_in_h (split to bf16 hi/lo), c0 = x@W_in_c^T + b_in_c
// ---------------------------------------------------------------------------
__global__ __launch_bounds__(256) void init_kernel(
    const float* __restrict__ inp, const float* __restrict__ Wh,
    const float* __restrict__ bh, const float* __restrict__ Wc,
    const float* __restrict__ bc,
    ushort* __restrict__ h_hi, ushort* __restrict__ h_lo, float* __restrict__ c)
{
    __shared__ float xs[64][128];  // 32KB
    int bid = blockIdx.x, tid = threadIdx.x;
    int ut = bid >> 2, bt = bid & 3;
    int U0 = ut * 16, b0 = bt * 64;
    float ah[4], ac[4];
#pragma unroll
    for (int j = 0; j < 4; ++j) {
        int p = tid + 256 * j;
        int U = U0 + (p & 15);
        ah[j] = bh[U];
        ac[j] = bc[U];
    }
    for (int kh = 0; kh < 2; ++kh) {
        __syncthreads();
        for (int i = tid; i < 64 * 128; i += 256)
            xs[i >> 7][i & 127] = inp[(size_t)(b0 + (i >> 7)) * INSZ + kh * 128 + (i & 127)];
        __syncthreads();
#pragma unroll
        for (int j = 0; j < 4; ++j) {
            int p = tid + 256 * j;
            int bl = p >> 4, ul = p & 15;
            int U = U0 + ul;
            const float* wh = Wh + (size_t)U * INSZ + kh * 128;
            const float* wc = Wc + (size_t)U * INSZ + kh * 128;
            float sh = 0.f, sc = 0.f;
            for (int k = 0; k < 128; ++k) {
                float x = xs[bl][k];
                sh += x * wh[k];
                sc += x * wc[k];
            }
            ah[j] += sh;
            ac[j] += sc;
        }
    }
#pragma unroll
    for (int j = 0; j < 4; ++j) {
        int p = tid + 256 * j;
        int bl = p >> 4, ul = p & 15;
        int gi = (b0 + bl) * HID + U0 + ul;
        ushort hh = f2bf(ah[j]);
        h_hi[gi] = hh;
        h_lo[gi] = f2bf(ah[j] - bf2f(hh));
        c[gi] = ac[j];
    }
}

// ---------------------------------------------------------------------------
// persist: cooperative persistent LSTM. 256 blocks (1/CU), 512 thr (8 waves).
// Identical to round 6 except grid.sync() -> gbar() tree barrier.
// ---------------------------------------------------------------------------
#define PERSIST_LDS (131072 + 128 * 36 * 4)  // Whi 64K + Wlo 64K + gl 18K

__global__ __launch_bounds__(512, 2) void persist_kernel(
    const ushort* __restrict__ Whi, const ushort* __restrict__ Wlo,
    const float* __restrict__ biasp, const float* __restrict__ c0,
    ushort* __restrict__ h0hi, ushort* __restrict__ h0lo,
    ushort* __restrict__ h1hi, ushort* __restrict__ h1lo,
    ushort* __restrict__ lstm, unsigned* bar)
{
    extern __shared__ char smem[];
    float* gl = (float*)(smem + 131072);  // [128][36] floats

    int tid = threadIdx.x;
    int bid = blockIdx.x;
    int ct = bid >> 1;   // col tile 0..127 (32 gate cols each)
    int hf = bid & 1;    // batch half
    int wave = tid >> 6, lane = tid & 63;
    int l15 = lane & 15, lk = (lane >> 4) * 8;

    // ---- stage weights into LDS (once), swizzled within each col's 2KB ----
    {
        const ushort* srcH = Whi + (size_t)ct * 32768;
        const ushort* srcL = Wlo + (size_t)ct * 32768;
#pragma unroll
        for (int i = 0; i < 8; ++i) {
            int o = (tid + i * 512) * 8;          // ushort idx in 32x1024
            int j = o >> 10;                      // col 0..31
            int kb = (o & 1023) * 2;              // byte in col, 16B-aligned
            int dst = (j * 2048 + kb) ^ ((j & 7) << 4);
            *(bf16x8*)(smem + dst) = *(const bf16x8*)(srcH + o);
            *(bf16x8*)(smem + 65536 + dst) = *(const bf16x8*)(srcL + o);
        }
    }
    // bias regs (fixed cols all steps)
    float bias0 = biasp[ct * 32 + l15];
    float bias1 = biasp[ct * 32 + 16 + l15];
    // c in registers: epilogue mapping p = tid + 512*pp -> (row=p>>3, unit=p&7)
    float creg[2];
    int erow0 = tid >> 3, eu0 = tid & 7;
    int erow1 = (tid + 512) >> 3, eu1 = tid & 7;
    creg[0] = c0[(size_t)(hf * 128 + erow0) * HID + ct * 8 + eu0];
    creg[1] = c0[(size_t)(hf * 128 + erow1) * HID + ct * 8 + eu1];
    __syncthreads();

    int r0 = hf * 128 + wave * 16 + l15;       // A-frag batch row
    const size_t arow = (size_t)r0 * HID + lk;
    // per-lane LDS B-frag swizzle constants
    int sw = (l15 & 7) << 4;
    int cbase0 = l15 * 2048;
    int cbase1 = (16 + l15) * 2048;
    int qbase = lk * 2;

    for (int t = 0; t < SEQ; ++t) {
        const ushort* hH = (t & 1) ? h1hi : h0hi;
        const ushort* hL = (t & 1) ? h1lo : h0lo;
        ushort* oH = (t & 1) ? h0hi : h1hi;
        ushort* oL = (t & 1) ? h0lo : h1lo;

        f32x4 acc0 = {}, acc1 = {};
        const ushort* ah = hH + arow;
        const ushort* al = hL + arow;
#pragma unroll 4
        for (int kk = 0; kk < 32; ++kk) {
            int q = (qbase + kk * 64) ^ sw;
            bf16x8 ahi = *(const bf16x8*)(ah + kk * 32);
            bf16x8 alo = *(const bf16x8*)(al + kk * 32);
            bf16x8 bh0 = *(const bf16x8*)(smem + cbase0 + q);
            bf16x8 bh1 = *(const bf16x8*)(smem + cbase1 + q);
            bf16x8 bl0 = *(const bf16x8*)(smem + 65536 + cbase0 + q);
            bf16x8 bl1 = *(const bf16x8*)(smem + 65536 + cbase1 + q);
            acc0 = MFMA(ahi, bh0, acc0);
            acc1 = MFMA(ahi, bh1, acc1);
            acc0 = MFMA(alo, bh0, acc0);
            acc1 = MFMA(alo, bh1, acc1);
            acc0 = MFMA(ahi, bl0, acc0);
            acc1 = MFMA(ahi, bl1, acc1);
        }

        // ---- dump biased gates to LDS for quad regroup ----
        int drow = wave * 16 + (lane >> 4) * 4;
#pragma unroll
        for (int r = 0; r < 4; ++r) {
            gl[(drow + r) * 36 + l15] = acc0[r] + bias0;
            gl[(drow + r) * 36 + 16 + l15] = acc1[r] + bias1;
        }
        __syncthreads();

        ushort* lst = lstm + (size_t)t * HID;
#pragma unroll
        for (int pp = 0; pp < 2; ++pp) {
            int row = pp ? erow1 : erow0;
            int ul = pp ? eu1 : eu0;
            float4 q4 = *(const float4*)((const char*)gl + row * 144 + ul * 16);
            float xi = q4.x, xf = q4.y, xg = q4.z, xo = q4.w;
            float ig = 1.f / (1.f + __expf(-xi));
            float fg = 1.f / (1.f + __expf(-xf));
            float xgc = fminf(fmaxf(xg, -30.f), 30.f);
            float eg = __expf(-2.f * xgc);
            float gg = (1.f - eg) / (1.f + eg);
            float og = 1.f / (1.f + __expf(-xo));
            float cn = fg * creg[pp] + ig * gg;
            creg[pp] = cn;
            float cc = fminf(fmaxf(cn, -30.f), 30.f);
            float ec = __expf(-2.f * cc);
            float th = (1.f - ec) / (1.f + ec);
            float h = og * th;
            int grow = hf * 128 + row;
            size_t gi = (size_t)grow * HID + ct * 8 + ul;
            ushort hh = f2bf(h);
            oH[gi] = hh;
            oL[gi] = f2bf(h - bf2f(hh));
            lst[(size_t)grow * (SEQ * HID) + ct * 8 + ul] = hh;
        }
        if (t < SEQ - 1) gbar(bar, bid, t);
    }
}

// ---------------------------------------------------------------------------
// step (FALLBACK ONLY, proven-correct round-2 path)
// ---------------------------------------------------------------------------
__global__ __launch_bounds__(512) void step_kernel(
    const ushort* __restrict__ hin_hi, const ushort* __restrict__ hin_lo,
    float* __restrict__ c,
    ushort* __restrict__ hout_hi, ushort* __restrict__ hout_lo,
    ushort* __restrict__ lstm_t,
    const ushort* __restrict__ Whi, const ushort* __restrict__ Wlo,
    const float* __restrict__ biasp)
{
    __shared__ float gl[64][65];
    int tid = threadIdx.x;
    int wave = tid >> 6, lane = tid & 63;
    int wm = wave >> 2, wn = wave & 3;
    int ntile = blockIdx.x & 63, mtile = blockIdx.x >> 6;
    int N0 = ntile * 64, b0 = mtile * 64;
    int l15 = lane & 15, lk = (lane >> 4) * 8;

    f32x4 acc0 = {}, acc1 = {};
    int row0 = b0 + wm * 32 + l15;
    int colj = N0 + wn * 16 + l15;

    for (int pass = 0; pass < 3; ++pass) {
        const ushort* Ap = (pass == 1) ? hin_lo : hin_hi;
        const ushort* Bp = (pass == 2) ? Wlo : Whi;
        const ushort* a0p = Ap + (size_t)row0 * HID + lk;
        const ushort* a1p = a0p + 16 * HID;
        const ushort* bp = Bp + (size_t)colj * HID + lk;
#pragma unroll 8
        for (int k0 = 0; k0 < 32; ++k0) {
            bf16x8 a0 = *(const bf16x8*)(a0p + k0 * 32);
            bf16x8 a1 = *(const bf16x8*)(a1p + k0 * 32);
            bf16x8 bb = *(const bf16x8*)(bp + k0 * 32);
            acc0 = MFMA(a0, bb, acc0);
            acc1 = MFMA(a1, bb, acc1);
        }
    }
    int cl = wn * 16 + l15;
    int rbase = wm * 32 + (lane >> 4) * 4;
#pragma unroll
    for (int r = 0; r < 4; ++r) {
        gl[rbase + r][cl] = acc0[r];
        gl[rbase + 16 + r][cl] = acc1[r];
    }
    __syncthreads();
#pragma unroll
    for (int pp = 0; pp < 2; ++pp) {
        int p = tid + 512 * pp;
        int bl = p >> 4, ul = p & 15;
        int jb = N0 + ul * 4;
        float xi = gl[bl][ul * 4 + 0] + biasp[jb + 0];
        float xf = gl[bl][ul * 4 + 1] + biasp[jb + 1];
        float xg = gl[bl][ul * 4 + 2] + biasp[jb + 2];
        float xo = gl[bl][ul * 4 + 3] + biasp[jb + 3];
        float ig = 1.f / (1.f + __expf(-xi));
        float fg = 1.f / (1.f + __expf(-xf));
        float xgc = fminf(fmaxf(xg, -30.f), 30.f);
        float eg = __expf(-2.f * xgc);
        float gg = (1.f - eg) / (1.f + eg);
        float og = 1.f / (1.f + __expf(-xo));
        int gidx = (b0 + bl) * HID + (N0 >> 2) + ul;
        float cn = fg * c[gidx] + ig * gg;
        float cc = fminf(fmaxf(cn, -30.f), 30.f);
        float ec = __expf(-2.f * cc);
        float th = (1.f - ec) / (1.f + ec);
        float h = og * th;
        c[gidx] = cn;
        ushort hh = f2bf(h);
        hout_hi[gidx] = hh;
        hout_lo[gidx] = f2bf(h - bf2f(hh));
        lstm_t[(size_t)(b0 + bl) * (SEQ * HID) + (N0 >> 2) + ul] = hh;
    }
}

// ---------------------------------------------------------------------------
// final: predictions[38400,128] = lstm_bf16 @ WoutB^T + b_out
// 1200 blocks x 512 thr (8 waves = 2 row x 4 col), 32-row tiles for TLP.
// ---------------------------------------------------------------------------
__global__ __launch_bounds__(512) void final_kernel(
    const ushort* __restrict__ lstm, const ushort* __restrict__ WoutB,
    const float* __restrict__ b_out, float* __restrict__ out)
{
    int tid = threadIdx.x;
    int wave = tid >> 6, lane = tid & 63;
    int wr = wave >> 2, wc = wave & 3;
    int m0 = blockIdx.x * 32;
    int l15 = lane & 15, lk = (lane >> 4) * 8;
    int r0 = m0 + wr * 16 + l15;
    int j0 = wc * 32 + l15;
    f32x4 acc0 = {}, acc1 = {};
    const ushort* ap = lstm + (size_t)r0 * HID + lk;
    const ushort* bp0 = WoutB + (size_t)j0 * HID + lk;
    const ushort* bp1 = bp0 + (size_t)16 * HID;
#pragma unroll 8
    for (int k0 = 0; k0 < 32; ++k0) {
        bf16x8 a = *(const bf16x8*)(ap + k0 * 32);
        bf16x8 b0 = *(const bf16x8*)(bp0 + k0 * 32);
        bf16x8 b1 = *(const bf16x8*)(bp1 + k0 * 32);
        acc0 = MFMA(a, b0, acc0);
        acc1 = MFMA(a, b1, acc1);
    }
#pragma unroll
    for (int r = 0; r < 4; ++r) {
        int rA = m0 + wr * 16 + (lane >> 4) * 4 + r;
        int c0 = wc * 32 + l15, c1 = c0 + 16;
        out[(size_t)rA * OUTSZ + c0] = acc0[r] + b_out[c0];
        out[(size_t)rA * OUTSZ + c1] = acc1[r] + b_out[c1];
    }
}

// ---------------------------------------------------------------------------
extern "C" void kernel_launch(void* const* d_in, const int* in_sizes, int n_in,
                              void* d_out, int out_size, void* d_ws, size_t ws_size,
                              hipStream_t stream)
{
    const float* init_input = (const float*)d_in[0];
    const float* W_in_h = (const float*)d_in[1];
    const float* b_in_h = (const float*)d_in[2];
    const float* W_in_c = (const float*)d_in[3];
    const float* b_in_c = (const float*)d_in[4];
    const float* W_hh = (const float*)d_in[5];
    const float* b_ih = (const float*)d_in[6];
    const float* b_hh = (const float*)d_in[7];
    const float* W_out = (const float*)d_in[8];
    const float* b_out = (const float*)d_in[9];
    float* out = (float*)d_out;

    char* ws = (char*)d_ws;
    ushort* Whi = (ushort*)(ws);                    // 8 MB
    ushort* Wlo = (ushort*)(ws + 8388608);          // 8 MB
    ushort* WoutB = (ushort*)(ws + 16777216);       // 256 KB
    float* biasp = (float*)(ws + 17039360);         // 16 KB
    ushort* hA_hi = (ushort*)(ws + 17055744);       // 512 KB
    ushort* hA_lo = (ushort*)(ws + 17580032);       // 512 KB
    ushort* hB_hi = (ushort*)(ws + 18104320);       // 512 KB
    ushort* hB_lo = (ushort*)(ws + 18628608);       // 512 KB
    float* cbuf = (float*)(ws + 19152896);          // 1 MB
    ushort* lstm = (ushort*)(ws + 20201472);        // 78.6 MB -> ends 98844672
    unsigned* bar = (unsigned*)(ws + 98844672);     // 4 KB barrier area

    hipLaunchKernelGGL(prep_kernel, dim3(4224), dim3(256), 0, stream,
                       W_hh, b_ih, b_hh, W_out, Whi, Wlo, WoutB, biasp);
    hipLaunchKernelGGL(init_kernel, dim3(256), dim3(256), 0, stream,
                       init_input, W_in_h, b_in_h, W_in_c, b_in_c,
                       hA_hi, hA_lo, cbuf);

    bool ok = (ws_size >= (size_t)98844672 + 4096);
    if (ok) {
        // zero barrier counters (ws is re-poisoned to 0xAA before every call)
        hipMemsetAsync(bar, 0, 4096, stream);
        hipFuncSetAttribute((const void*)persist_kernel,
                            hipFuncAttributeMaxDynamicSharedMemorySize, PERSIST_LDS);
        const ushort* a0 = Whi; const ushort* a1 = Wlo;
        const float* a2 = biasp; const float* a3 = cbuf;
        ushort* a4 = hA_hi; ushort* a5 = hA_lo;
        ushort* a6 = hB_hi; ushort* a7 = hB_lo;
        ushort* a8 = lstm; unsigned* a9 = bar;
        void* kargs[] = {(void*)&a0, (void*)&a1, (void*)&a2, (void*)&a3,
                         (void*)&a4, (void*)&a5, (void*)&a6, (void*)&a7,
                         (void*)&a8, (void*)&a9};
        hipError_t e = hipLaunchCooperativeKernel((void*)persist_kernel,
                                                  dim3(256), dim3(512), kargs,
                                                  PERSIST_LDS, stream);
        if (e != hipSuccess) ok = false;
    }
    if (!ok) {
        // fallback: proven per-step launch path
        for (int t = 0; t < SEQ; ++t) {
            const ushort* ih = (t & 1) ? hB_hi : hA_hi;
            const ushort* il = (t & 1) ? hB_lo : hA_lo;
            ushort* oh = (t & 1) ? hA_hi : hB_hi;
            ushort* ol = (t & 1) ? hA_lo : hB_lo;
            hipLaunchKernelGGL(step_kernel, dim3(256), dim3(512), 0, stream,
                               ih, il, cbuf, oh, ol, lstm + (size_t)t * HID,
                               Whi, Wlo, biasp);
        }
    }
    hipLaunchKernelGGL(final_kernel, dim3(1200), dim3(512), 0, stream,
                       lstm, WoutB, b_out, out);
}

// Round 8
// 4933.712 us; speedup vs baseline: 2.0504x; 1.1181x over previous
//
#include <hip/hip_runtime.h>
#include <hip/hip_bf16.h>

#define BATCH 256
#define INSZ 256
#define HID 1024
#define OUTSZ 128
#define SEQ 150
#define NG 4096  // 4*HID

typedef __attribute__((ext_vector_type(8))) short bf16x8;
typedef __attribute__((ext_vector_type(4))) float f32x4;
typedef unsigned long long ull;

#define MFMA(a, b, c) __builtin_amdgcn_mfma_f32_16x16x32_bf16(a, b, c, 0, 0, 0)

static __device__ __forceinline__ float bf2f(ushort u) {
    union { unsigned int i; float f; } v;
    v.i = ((unsigned int)u) << 16;
    return v.f;
}
static __device__ __forceinline__ ushort f2bf(float f) {
    union { float f; unsigned int i; } v;
    v.f = f;
    unsigned int x = v.i;
    return (ushort)((x + 0x7fffu + ((x >> 16) & 1u)) >> 16);
}

// agent-scope (sc1, IC-coherent) 16B load as bf16x8: two relaxed ull atomic loads
static __device__ __forceinline__ bf16x8 ldg_agent16(const ushort* p) {
    union { ull u[2]; bf16x8 v; } r;
    ull* q = (ull*)p;
    r.u[0] = __hip_atomic_load(q + 0, __ATOMIC_RELAXED, __HIP_MEMORY_SCOPE_AGENT);
    r.u[1] = __hip_atomic_load(q + 1, __ATOMIC_RELAXED, __HIP_MEMORY_SCOPE_AGENT);
    return r.v;
}

// ---------------------------------------------------------------------------
// Two-level agent-scope grid barrier, NO cache-maintenance fences (r7's two
// __threadfence()s = full per-XCD L2 wb/inv per block per step ~= the 33us/step
// residual). All cross-block data moves via sc1 atomics (IC-coherent), so a
// pure relaxed rendezvous suffices: __syncthreads() drains vmcnt (stores acked
// at IC) before arrival; readers' sc1 loads can't see stale L2.
// bar layout (uints): [g*16] g=0..15 group counters (64B apart), [512] root,
// [544] release flag. Monotonic targets; no reset.
// ---------------------------------------------------------------------------
static __device__ __forceinline__ void gbar(unsigned* bar, int bid, int t) {
    __syncthreads();  // compiler emits s_waitcnt vmcnt(0) before s_barrier
    if (threadIdx.x == 0) {
        asm volatile("s_waitcnt vmcnt(0)" ::: "memory");
        int g = bid >> 4;
        unsigned tgt = (unsigned)(16 * (t + 1));
        unsigned a = __hip_atomic_fetch_add(&bar[g * 16], 1u,
                                            __ATOMIC_RELAXED, __HIP_MEMORY_SCOPE_AGENT);
        if (a == tgt - 1u) {
            unsigned r = __hip_atomic_fetch_add(&bar[512], 1u,
                                                __ATOMIC_RELAXED, __HIP_MEMORY_SCOPE_AGENT);
            if (r == tgt - 1u) {
                __hip_atomic_store(&bar[544], (unsigned)(t + 1),
                                   __ATOMIC_RELAXED, __HIP_MEMORY_SCOPE_AGENT);
            }
        }
        while (__hip_atomic_load(&bar[544], __ATOMIC_RELAXED,
                                 __HIP_MEMORY_SCOPE_AGENT) < (unsigned)(t + 1)) {
            __builtin_amdgcn_s_sleep(2);
        }
    }
    __syncthreads();
}

// ---------------------------------------------------------------------------
// prep: build gate-permuted split-bf16 W_hh (row 4u+g = W_hh[g*H+u]), fused
// bias, and bf16 W_out. (Also feeds the fallback path.)
// ---------------------------------------------------------------------------
__global__ __launch_bounds__(256) void prep_kernel(
    const float* __restrict__ Whh, const float* __restrict__ b_ih,
    const float* __restrict__ b_hh, const float* __restrict__ Wout,
    ushort* __restrict__ Whi, ushort* __restrict__ Wlo,
    ushort* __restrict__ WoutB, float* __restrict__ biasp)
{
    int bid = blockIdx.x, tid = threadIdx.x;
    if (bid < NG) {
        int u = bid >> 2, g = bid & 3;
        const float* src = Whh + (size_t)(g * HID + u) * HID;
        ushort* dhi = Whi + (size_t)bid * HID;
        ushort* dlo = Wlo + (size_t)bid * HID;
#pragma unroll
        for (int i = 0; i < 4; ++i) {
            int k = tid + 256 * i;
            float w = src[k];
            ushort hi = f2bf(w);
            dhi[k] = hi;
            dlo[k] = f2bf(w - bf2f(hi));
        }
        if (tid == 0) biasp[bid] = b_ih[g * HID + u] + b_hh[g * HID + u];
    } else {
        int r = bid - NG;
#pragma unroll
        for (int i = 0; i < 4; ++i) {
            int k = tid + 256 * i;
            WoutB[(size_t)r * HID + k] = f2bf(Wout[(size_t)r * HID + k]);
        }
    }
}

// ---------------------------------------------------------------------------
// init: h0 = x@W_in_h^T + b_in_h (split to bf16 hi/lo), c0 = x@W_in_c^T + b_in_c
// ---------------------------------------------------------------------------
__global__ __launch_bounds__(256) void init_kernel(
    const float* __restrict__ inp, const float* __restrict__ Wh,
    const float* __restrict__ bh, const float* __restrict__ Wc,
    const float* __restrict__ bc,
    ushort* __restrict__ h_hi, ushort* __restrict__ h_lo, float* __restrict__ c)
{
    __shared__ float xs[64][128];  // 32KB
    int bid = blockIdx.x, tid = threadIdx.x;
    int ut = bid >> 2, bt = bid & 3;
    int U0 = ut * 16, b0 = bt * 64;
    float ah[4], ac[4];
#pragma unroll
    for (int j = 0; j < 4; ++j) {
        int p = tid + 256 * j;
        int U = U0 + (p & 15);
        ah[j] = bh[U];
        ac[j] = bc[U];
    }
    for (int kh = 0; kh < 2; ++kh) {
        __syncthreads();
        for (int i = tid; i < 64 * 128; i += 256)
            xs[i >> 7][i & 127] = inp[(size_t)(b0 + (i >> 7)) * INSZ + kh * 128 + (i & 127)];
        __syncthreads();
#pragma unroll
        for (int j = 0; j < 4; ++j) {
            int p = tid + 256 * j;
            int bl = p >> 4, ul = p & 15;
            int U = U0 + ul;
            const float* wh = Wh + (size_t)U * INSZ + kh * 128;
            const float* wc = Wc + (size_t)U * INSZ + kh * 128;
            float sh = 0.f, sc = 0.f;
            for (int k = 0; k < 128; ++k) {
                float x = xs[bl][k];
                sh += x * wh[k];
                sc += x * wc[k];
            }
            ah[j] += sh;
            ac[j] += sc;
        }
    }
#pragma unroll
    for (int j = 0; j < 4; ++j) {
        int p = tid + 256 * j;
        int bl = p >> 4, ul = p & 15;
        int gi = (b0 + bl) * HID + U0 + ul;
        ushort hh = f2bf(ah[j]);
        h_hi[gi] = hh;
        h_lo[gi] = f2bf(ah[j] - bf2f(hh));
        c[gi] = ac[j];
    }
}

// ---------------------------------------------------------------------------
// persist: cooperative persistent LSTM. 256 blocks (1/CU), 512 thr (8 waves).
// r7 structure; h transport switched to agent-scope (sc1/IC) atomics and the
// barrier is fence-free. Weights stay in swizzled LDS all 150 steps; c in regs.
// ---------------------------------------------------------------------------
#define PERSIST_LDS (131072 + 128 * 36 * 4)  // Whi 64K + Wlo 64K + gl 18K

__global__ __launch_bounds__(512, 2) void persist_kernel(
    const ushort* __restrict__ Whi, const ushort* __restrict__ Wlo,
    const float* __restrict__ biasp, const float* __restrict__ c0,
    ushort* __restrict__ h0hi, ushort* __restrict__ h0lo,
    ushort* __restrict__ h1hi, ushort* __restrict__ h1lo,
    ushort* __restrict__ lstm, unsigned* bar)
{
    extern __shared__ char smem[];
    float* gl = (float*)(smem + 131072);  // [128][36] floats

    int tid = threadIdx.x;
    int bid = blockIdx.x;
    int ct = bid >> 1;   // col tile 0..127 (32 gate cols each)
    int hf = bid & 1;    // batch half
    int wave = tid >> 6, lane = tid & 63;
    int l15 = lane & 15, lk = (lane >> 4) * 8;

    // ---- stage weights into LDS (once), swizzled within each col's 2KB ----
    {
        const ushort* srcH = Whi + (size_t)ct * 32768;
        const ushort* srcL = Wlo + (size_t)ct * 32768;
#pragma unroll
        for (int i = 0; i < 8; ++i) {
            int o = (tid + i * 512) * 8;          // ushort idx in 32x1024
            int j = o >> 10;                      // col 0..31
            int kb = (o & 1023) * 2;              // byte in col, 16B-aligned
            int dst = (j * 2048 + kb) ^ ((j & 7) << 4);
            *(bf16x8*)(smem + dst) = *(const bf16x8*)(srcH + o);
            *(bf16x8*)(smem + 65536 + dst) = *(const bf16x8*)(srcL + o);
        }
    }
    // bias regs (fixed cols all steps)
    float bias0 = biasp[ct * 32 + l15];
    float bias1 = biasp[ct * 32 + 16 + l15];
    // c in registers: epilogue mapping p = tid + 512*pp -> (row=p>>3, unit=p&7)
    float creg[2];
    int erow0 = tid >> 3, eu0 = tid & 7;
    int erow1 = (tid + 512) >> 3, eu1 = tid & 7;
    creg[0] = c0[(size_t)(hf * 128 + erow0) * HID + ct * 8 + eu0];
    creg[1] = c0[(size_t)(hf * 128 + erow1) * HID + ct * 8 + eu1];
    __syncthreads();

    int r0 = hf * 128 + wave * 16 + l15;       // A-frag batch row
    const size_t arow = (size_t)r0 * HID + lk;
    // per-lane LDS B-frag swizzle constants
    int sw = (l15 & 7) << 4;
    int cbase0 = l15 * 2048;
    int cbase1 = (16 + l15) * 2048;
    int qbase = lk * 2;

    for (int t = 0; t < SEQ; ++t) {
        const ushort* hH = (t & 1) ? h1hi : h0hi;
        const ushort* hL = (t & 1) ? h1lo : h0lo;
        ushort* oH = (t & 1) ? h0hi : h1hi;
        ushort* oL = (t & 1) ? h0lo : h1lo;

        f32x4 acc0 = {}, acc1 = {};
        const ushort* ah = hH + arow;
        const ushort* al = hL + arow;
#pragma unroll 4
        for (int kk = 0; kk < 32; ++kk) {
            int q = (qbase + kk * 64) ^ sw;
            bf16x8 ahi = ldg_agent16(ah + kk * 32);
            bf16x8 alo = ldg_agent16(al + kk * 32);
            bf16x8 bh0 = *(const bf16x8*)(smem + cbase0 + q);
            bf16x8 bh1 = *(const bf16x8*)(smem + cbase1 + q);
            bf16x8 bl0 = *(const bf16x8*)(smem + 65536 + cbase0 + q);
            bf16x8 bl1 = *(const bf16x8*)(smem + 65536 + cbase1 + q);
            acc0 = MFMA(ahi, bh0, acc0);
            acc1 = MFMA(ahi, bh1, acc1);
            acc0 = MFMA(alo, bh0, acc0);
            acc1 = MFMA(alo, bh1, acc1);
            acc0 = MFMA(ahi, bl0, acc0);
            acc1 = MFMA(ahi, bl1, acc1);
        }

        // ---- dump biased gates to LDS for quad regroup ----
        int drow = wave * 16 + (lane >> 4) * 4;
#pragma unroll
        for (int r = 0; r < 4; ++r) {
            gl[(drow + r) * 36 + l15] = acc0[r] + bias0;
            gl[(drow + r) * 36 + 16 + l15] = acc1[r] + bias1;
        }
        __syncthreads();

        ushort* lst = lstm + (size_t)t * HID;
#pragma unroll
        for (int pp = 0; pp < 2; ++pp) {
            int row = pp ? erow1 : erow0;
            int ul = pp ? eu1 : eu0;
            float4 q4 = *(const float4*)((const char*)gl + row * 144 + ul * 16);
            float xi = q4.x, xf = q4.y, xg = q4.z, xo = q4.w;
            float ig = 1.f / (1.f + __expf(-xi));
            float fg = 1.f / (1.f + __expf(-xf));
            float xgc = fminf(fmaxf(xg, -30.f), 30.f);
            float eg = __expf(-2.f * xgc);
            float gg = (1.f - eg) / (1.f + eg);
            float og = 1.f / (1.f + __expf(-xo));
            float cn = fg * creg[pp] + ig * gg;
            creg[pp] = cn;
            float cc = fminf(fmaxf(cn, -30.f), 30.f);
            float ec = __expf(-2.f * cc);
            float th = (1.f - ec) / (1.f + ec);
            float h = og * th;
            int grow = hf * 128 + row;
            size_t gi = (size_t)grow * HID + ct * 8 + ul;
            ushort hh = f2bf(h);
            ushort hl = f2bf(h - bf2f(hh));
            __hip_atomic_store(&oH[gi], hh, __ATOMIC_RELAXED, __HIP_MEMORY_SCOPE_AGENT);
            __hip_atomic_store(&oL[gi], hl, __ATOMIC_RELAXED, __HIP_MEMORY_SCOPE_AGENT);
            lst[(size_t)grow * (SEQ * HID) + ct * 8 + ul] = hh;
        }
        if (t < SEQ - 1) gbar(bar, bid, t);
    }
}

// ---------------------------------------------------------------------------
// step (FALLBACK ONLY, proven-correct round-2 path)
// ---------------------------------------------------------------------------
__global__ __launch_bounds__(512) void step_kernel(
    const ushort* __restrict__ hin_hi, const ushort* __restrict__ hin_lo,
    float* __restrict__ c,
    ushort* __restrict__ hout_hi, ushort* __restrict__ hout_lo,
    ushort* __restrict__ lstm_t,
    const ushort* __restrict__ Whi, const ushort* __restrict__ Wlo,
    const float* __restrict__ biasp)
{
    __shared__ float gl[64][65];
    int tid = threadIdx.x;
    int wave = tid >> 6, lane = tid & 63;
    int wm = wave >> 2, wn = wave & 3;
    int ntile = blockIdx.x & 63, mtile = blockIdx.x >> 6;
    int N0 = ntile * 64, b0 = mtile * 64;
    int l15 = lane & 15, lk = (lane >> 4) * 8;

    f32x4 acc0 = {}, acc1 = {};
    int row0 = b0 + wm * 32 + l15;
    int colj = N0 + wn * 16 + l15;

    for (int pass = 0; pass < 3; ++pass) {
        const ushort* Ap = (pass == 1) ? hin_lo : hin_hi;
        const ushort* Bp = (pass == 2) ? Wlo : Whi;
        const ushort* a0p = Ap + (size_t)row0 * HID + lk;
        const ushort* a1p = a0p + 16 * HID;
        const ushort* bp = Bp + (size_t)colj * HID + lk;
#pragma unroll 8
        for (int k0 = 0; k0 < 32; ++k0) {
            bf16x8 a0 = *(const bf16x8*)(a0p + k0 * 32);
            bf16x8 a1 = *(const bf16x8*)(a1p + k0 * 32);
            bf16x8 bb = *(const bf16x8*)(bp + k0 * 32);
            acc0 = MFMA(a0, bb, acc0);
            acc1 = MFMA(a1, bb, acc1);
        }
    }
    int cl = wn * 16 + l15;
    int rbase = wm * 32 + (lane >> 4) * 4;
#pragma unroll
    for (int r = 0; r < 4; ++r) {
        gl[rbase + r][cl] = acc0[r];
        gl[rbase + 16 + r][cl] = acc1[r];
    }
    __syncthreads();
#pragma unroll
    for (int pp = 0; pp < 2; ++pp) {
        int p = tid + 512 * pp;
        int bl = p >> 4, ul = p & 15;
        int jb = N0 + ul * 4;
        float xi = gl[bl][ul * 4 + 0] + biasp[jb + 0];
        float xf = gl[bl][ul * 4 + 1] + biasp[jb + 1];
        float xg = gl[bl][ul * 4 + 2] + biasp[jb + 2];
        float xo = gl[bl][ul * 4 + 3] + biasp[jb + 3];
        float ig = 1.f / (1.f + __expf(-xi));
        float fg = 1.f / (1.f + __expf(-xf));
        float xgc = fminf(fmaxf(xg, -30.f), 30.f);
        float eg = __expf(-2.f * xgc);
        float gg = (1.f - eg) / (1.f + eg);
        float og = 1.f / (1.f + __expf(-xo));
        int gidx = (b0 + bl) * HID + (N0 >> 2) + ul;
        float cn = fg * c[gidx] + ig * gg;
        float cc = fminf(fmaxf(cn, -30.f), 30.f);
        float ec = __expf(-2.f * cc);
        float th = (1.f - ec) / (1.f + ec);
        float h = og * th;
        c[gidx] = cn;
        ushort hh = f2bf(h);
        hout_hi[gidx] = hh;
        hout_lo[gidx] = f2bf(h - bf2f(hh));
        lstm_t[(size_t)(b0 + bl) * (SEQ * HID) + (N0 >> 2) + ul] = hh;
    }
}

// ---------------------------------------------------------------------------
// final: predictions[38400,128] = lstm_bf16 @ WoutB^T + b_out
// 1200 blocks x 512 thr (8 waves = 2 row x 4 col), 32-row tiles for TLP.
// ---------------------------------------------------------------------------
__global__ __launch_bounds__(512) void final_kernel(
    const ushort* __restrict__ lstm, const ushort* __restrict__ WoutB,
    const float* __restrict__ b_out, float* __restrict__ out)
{
    int tid = threadIdx.x;
    int wave = tid >> 6, lane = tid & 63;
    int wr = wave >> 2, wc = wave & 3;
    int m0 = blockIdx.x * 32;
    int l15 = lane & 15, lk = (lane >> 4) * 8;
    int r0 = m0 + wr * 16 + l15;
    int j0 = wc * 32 + l15;
    f32x4 acc0 = {}, acc1 = {};
    const ushort* ap = lstm + (size_t)r0 * HID + lk;
    const ushort* bp0 = WoutB + (size_t)j0 * HID + lk;
    const ushort* bp1 = bp0 + (size_t)16 * HID;
#pragma unroll 8
    for (int k0 = 0; k0 < 32; ++k0) {
        bf16x8 a = *(const bf16x8*)(ap + k0 * 32);
        bf16x8 b0 = *(const bf16x8*)(bp0 + k0 * 32);
        bf16x8 b1 = *(const bf16x8*)(bp1 + k0 * 32);
        acc0 = MFMA(a, b0, acc0);
        acc1 = MFMA(a, b1, acc1);
    }
#pragma unroll
    for (int r = 0; r < 4; ++r) {
        int rA = m0 + wr * 16 + (lane >> 4) * 4 + r;
        int c0 = wc * 32 + l15, c1 = c0 + 16;
        out[(size_t)rA * OUTSZ + c0] = acc0[r] + b_out[c0];
        out[(size_t)rA * OUTSZ + c1] = acc1[r] + b_out[c1];
    }
}

// ---------------------------------------------------------------------------
extern "C" void kernel_launch(void* const* d_in, const int* in_sizes, int n_in,
                              void* d_out, int out_size, void* d_ws, size_t ws_size,
                              hipStream_t stream)
{
    const float* init_input = (const float*)d_in[0];
    const float* W_in_h = (const float*)d_in[1];
    const float* b_in_h = (const float*)d_in[2];
    const float* W_in_c = (const float*)d_in[3];
    const float* b_in_c = (const float*)d_in[4];
    const float* W_hh = (const float*)d_in[5];
    const float* b_ih = (const float*)d_in[6];
    const float* b_hh = (const float*)d_in[7];
    const float* W_out = (const float*)d_in[8];
    const float* b_out = (const float*)d_in[9];
    float* out = (float*)d_out;

    char* ws = (char*)d_ws;
    ushort* Whi = (ushort*)(ws);                    // 8 MB
    ushort* Wlo = (ushort*)(ws + 8388608);          // 8 MB
    ushort* WoutB = (ushort*)(ws + 16777216);       // 256 KB
    float* biasp = (float*)(ws + 17039360);         // 16 KB
    ushort* hA_hi = (ushort*)(ws + 17055744);       // 512 KB
    ushort* hA_lo = (ushort*)(ws + 17580032);       // 512 KB
    ushort* hB_hi = (ushort*)(ws + 18104320);       // 512 KB
    ushort* hB_lo = (ushort*)(ws + 18628608);       // 512 KB
    float* cbuf = (float*)(ws + 19152896);          // 1 MB
    ushort* lstm = (ushort*)(ws + 20201472);        // 78.6 MB -> ends 98844672
    unsigned* bar = (unsigned*)(ws + 98844672);     // 4 KB barrier area

    hipLaunchKernelGGL(prep_kernel, dim3(4224), dim3(256), 0, stream,
                       W_hh, b_ih, b_hh, W_out, Whi, Wlo, WoutB, biasp);
    hipLaunchKernelGGL(init_kernel, dim3(256), dim3(256), 0, stream,
                       init_input, W_in_h, b_in_h, W_in_c, b_in_c,
                       hA_hi, hA_lo, cbuf);

    bool ok = (ws_size >= (size_t)98844672 + 4096);
    if (ok) {
        // zero barrier counters (ws is re-poisoned to 0xAA before every call)
        hipMemsetAsync(bar, 0, 4096, stream);
        hipFuncSetAttribute((const void*)persist_kernel,
                            hipFuncAttributeMaxDynamicSharedMemorySize, PERSIST_LDS);
        const ushort* a0 = Whi; const ushort* a1 = Wlo;
        const float* a2 = biasp; const float* a3 = cbuf;
        ushort* a4 = hA_hi; ushort* a5 = hA_lo;
        ushort* a6 = hB_hi; ushort* a7 = hB_lo;
        ushort* a8 = lstm; unsigned* a9 = bar;
        void* kargs[] = {(void*)&a0, (void*)&a1, (void*)&a2, (void*)&a3,
                         (void*)&a4, (void*)&a5, (void*)&a6, (void*)&a7,
                         (void*)&a8, (void*)&a9};
        hipError_t e = hipLaunchCooperativeKernel((void*)persist_kernel,
                                                  dim3(256), dim3(512), kargs,
                                                  PERSIST_LDS, stream);
        if (e != hipSuccess) ok = false;
    }
    if (!ok) {
        // fallback: proven per-step launch path
        for (int t = 0; t < SEQ; ++t) {
            const ushort* ih = (t & 1) ? hB_hi : hA_hi;
            const ushort* il = (t & 1) ? hB_lo : hA_lo;
            ushort* oh = (t & 1) ? hA_hi : hB_hi;
            ushort* ol = (t & 1) ? hA_lo : hB_lo;
            hipLaunchKernelGGL(step_kernel, dim3(256), dim3(512), 0, stream,
                               ih, il, cbuf, oh, ol, lstm + (size_t)t * HID,
                               Whi, Wlo, biasp);
        }
    }
    hipLaunchKernelGGL(final_kernel, dim3(1200), dim3(512), 0, stream,
                       lstm, WoutB, b_out, out);
}

// Round 11
// 2861.682 us; speedup vs baseline: 3.5351x; 1.7241x over previous
//
#include <hip/hip_runtime.h>
#include <hip/hip_bf16.h>

#define BATCH 256
#define INSZ 256
#define HID 1024
#define OUTSZ 128
#define SEQ 150
#define NG 4096   // 4*HID
#define SH (SEQ * HID)  // 153600

typedef __attribute__((ext_vector_type(8))) short bf16x8;
typedef __attribute__((ext_vector_type(4))) float f32x4;
typedef unsigned long long ull;

#define MFMA(a, b, c) __builtin_amdgcn_mfma_f32_16x16x32_bf16(a, b, c, 0, 0, 0)

static __device__ __forceinline__ float bf2f(ushort u) {
    union { unsigned int i; float f; } v;
    v.i = ((unsigned int)u) << 16;
    return v.f;
}
static __device__ __forceinline__ ushort f2bf(float f) {
    union { float f; unsigned int i; } v;
    v.f = f;
    unsigned int x = v.i;
    return (ushort)((x + 0x7fffu + ((x >> 16) & 1u)) >> 16);
}

// agent-scope (sc1, IC-coherent) 16B load as bf16x8 (mode-B fallback path)
static __device__ __forceinline__ bf16x8 ldg_agent16(const ushort* p) {
    union { ull u[2]; bf16x8 v; } r;
    ull* q = (ull*)p;
    r.u[0] = __hip_atomic_load(q + 0, __ATOMIC_RELAXED, __HIP_MEMORY_SCOPE_AGENT);
    r.u[1] = __hip_atomic_load(q + 1, __ATOMIC_RELAXED, __HIP_MEMORY_SCOPE_AGENT);
    return r.v;
}

// ---------------------------------------------------------------------------
// Two-level agent-scope grid barrier, fence-free (r7/r8 lineage). bar layout
// (uints): [g*16] g=0..15 group counters (64B apart), [512] root, [544] flag.
// Monotonic targets; no reset. Cross-block data is IC-coherent by construction
// (sc1 stores + either sc1 loads (mode B) or never-reused addresses (mode A)),
// so a relaxed rendezvous suffices.
// ---------------------------------------------------------------------------
static __device__ __forceinline__ void gbar(unsigned* bar, int bid, int t) {
    __syncthreads();  // compiler emits s_waitcnt vmcnt(0) before s_barrier
    if (threadIdx.x == 0) {
        asm volatile("s_waitcnt vmcnt(0)" ::: "memory");
        int g = bid >> 4;
        unsigned tgt = (unsigned)(16 * (t + 1));
        unsigned a = __hip_atomic_fetch_add(&bar[g * 16], 1u,
                                            __ATOMIC_RELAXED, __HIP_MEMORY_SCOPE_AGENT);
        if (a == tgt - 1u) {
            unsigned r = __hip_atomic_fetch_add(&bar[512], 1u,
                                                __ATOMIC_RELAXED, __HIP_MEMORY_SCOPE_AGENT);
            if (r == tgt - 1u) {
                __hip_atomic_store(&bar[544], (unsigned)(t + 1),
                                   __ATOMIC_RELAXED, __HIP_MEMORY_SCOPE_AGENT);
            }
        }
        while (__hip_atomic_load(&bar[544], __ATOMIC_RELAXED,
                                 __HIP_MEMORY_SCOPE_AGENT) < (unsigned)(t + 1)) {
            __builtin_amdgcn_s_sleep(2);
        }
    }
    __syncthreads();
}

// ---------------------------------------------------------------------------
// prep: gate-permuted split-bf16 W_hh (row 4u+g = W_hh[g*H+u]), fused bias,
// bf16 W_out.
// ---------------------------------------------------------------------------
__global__ __launch_bounds__(256) void prep_kernel(
    const float* __restrict__ Whh, const float* __restrict__ b_ih,
    const float* __restrict__ b_hh, const float* __restrict__ Wout,
    ushort* __restrict__ Whi, ushort* __restrict__ Wlo,
    ushort* __restrict__ WoutB, float* __restrict__ biasp)
{
    int bid = blockIdx.x, tid = threadIdx.x;
    if (bid < NG) {
        int u = bid >> 2, g = bid & 3;
        const float* src = Whh + (size_t)(g * HID + u) * HID;
        ushort* dhi = Whi + (size_t)bid * HID;
        ushort* dlo = Wlo + (size_t)bid * HID;
#pragma unroll
        for (int i = 0; i < 4; ++i) {
            int k = tid + 256 * i;
            float w = src[k];
            ushort hi = f2bf(w);
            dhi[k] = hi;
            dlo[k] = f2bf(w - bf2f(hi));
        }
        if (tid == 0) biasp[bid] = b_ih[g * HID + u] + b_hh[g * HID + u];
    } else {
        int r = bid - NG;
#pragma unroll
        for (int i = 0; i < 4; ++i) {
            int k = tid + 256 * i;
            WoutB[(size_t)r * HID + k] = f2bf(Wout[(size_t)r * HID + k]);
        }
    }
}

// ---------------------------------------------------------------------------
// init: h0 = x@W_in_h^T + b_in_h (split hi/lo), c0 = x@W_in_c^T + b_in_c
// ---------------------------------------------------------------------------
__global__ __launch_bounds__(256) void init_kernel(
    const float* __restrict__ inp, const float* __restrict__ Wh,
    const float* __restrict__ bh, const float* __restrict__ Wc,
    const float* __restrict__ bc,
    ushort* __restrict__ h_hi, ushort* __restrict__ h_lo, float* __restrict__ c)
{
    __shared__ float xs[64][128];  // 32KB
    int bid = blockIdx.x, tid = threadIdx.x;
    int ut = bid >> 2, bt = bid & 3;
    int U0 = ut * 16, b0 = bt * 64;
    float ah[4], ac[4];
#pragma unroll
    for (int j = 0; j < 4; ++j) {
        int p = tid + 256 * j;
        int U = U0 + (p & 15);
        ah[j] = bh[U];
        ac[j] = bc[U];
    }
    for (int kh = 0; kh < 2; ++kh) {
        __syncthreads();
        for (int i = tid; i < 64 * 128; i += 256)
            xs[i >> 7][i & 127] = inp[(size_t)(b0 + (i >> 7)) * INSZ + kh * 128 + (i & 127)];
        __syncthreads();
#pragma unroll
        for (int j = 0; j < 4; ++j) {
            int p = tid + 256 * j;
            int bl = p >> 4, ul = p & 15;
            int U = U0 + ul;
            const float* wh = Wh + (size_t)U * INSZ + kh * 128;
            const float* wc = Wc + (size_t)U * INSZ + kh * 128;
            float sh = 0.f, sc = 0.f;
            for (int k = 0; k < 128; ++k) {
                float x = xs[bl][k];
                sh += x * wh[k];
                sc += x * wc[k];
            }
            ah[j] += sh;
            ac[j] += sc;
        }
    }
#pragma unroll
    for (int j = 0; j < 4; ++j) {
        int p = tid + 256 * j;
        int bl = p >> 4, ul = p & 15;
        int gi = (b0 + bl) * HID + U0 + ul;
        ushort hh = f2bf(ah[j]);
        h_hi[gi] = hh;
        h_lo[gi] = f2bf(ah[j] - bf2f(hh));
        c[gi] = ac[j];
    }
}

// ---------------------------------------------------------------------------
// persist_seq (MODE A): write-once h transport. Step s reads h_s from
// lstm/hlo slot s-1 (s=0: init buffers) with PLAIN cached loads — addresses
// are never rewritten, so no staleness; L2 serves the 32-blocks/XCD multicast
// and the IC sees only line refills (r8 was sc1-per-load = IC request-rate
// bound, ~27us/step). Writes go sc1 (write-through) so post-barrier refills
// see fresh data. Weights in swizzled LDS all 150 steps; c in registers.
// ---------------------------------------------------------------------------
#define PERSIST_LDS (131072 + 128 * 36 * 4)  // Whi 64K + Wlo 64K + gl 18K

__global__ __launch_bounds__(512, 2) void persist_seq(
    const ushort* __restrict__ Whi, const ushort* __restrict__ Wlo,
    const float* __restrict__ biasp, const float* __restrict__ c0,
    const ushort* __restrict__ h0hi, const ushort* __restrict__ h0lo,
    ushort* __restrict__ lstm, ushort* __restrict__ hlo, unsigned* bar)
{
    extern __shared__ char smem[];
    float* gl = (float*)(smem + 131072);  // [128][36] floats

    int tid = threadIdx.x;
    int bid = blockIdx.x;
    int ct = bid >> 1;   // col tile 0..127 (32 gate cols each)
    int hf = bid & 1;    // batch half
    int wave = tid >> 6, lane = tid & 63;
    int l15 = lane & 15, lk = (lane >> 4) * 8;

    // ---- stage weights into LDS (once), swizzled within each col's 2KB ----
    {
        const ushort* srcH = Whi + (size_t)ct * 32768;
        const ushort* srcL = Wlo + (size_t)ct * 32768;
#pragma unroll
        for (int i = 0; i < 8; ++i) {
            int o = (tid + i * 512) * 8;          // ushort idx in 32x1024
            int j = o >> 10;                      // col 0..31
            int kb = (o & 1023) * 2;              // byte in col, 16B-aligned
            int dst = (j * 2048 + kb) ^ ((j & 7) << 4);
            *(bf16x8*)(smem + dst) = *(const bf16x8*)(srcH + o);
            *(bf16x8*)(smem + 65536 + dst) = *(const bf16x8*)(srcL + o);
        }
    }
    float bias0 = biasp[ct * 32 + l15];
    float bias1 = biasp[ct * 32 + 16 + l15];
    float creg[2];
    int erow0 = tid >> 3, eu0 = tid & 7;
    int erow1 = (tid + 512) >> 3, eu1 = tid & 7;
    creg[0] = c0[(size_t)(hf * 128 + erow0) * HID + ct * 8 + eu0];
    creg[1] = c0[(size_t)(hf * 128 + erow1) * HID + ct * 8 + eu1];
    __syncthreads();

    int r0 = hf * 128 + wave * 16 + l15;       // A-frag batch row
    const size_t arow0 = (size_t)r0 * HID + lk;     // h0 layout [B][HID]
    const size_t arowT = (size_t)r0 * SH + lk;      // transport layout [B][SEQ][HID]
    int sw = (l15 & 7) << 4;
    int cbase0 = l15 * 2048;
    int cbase1 = (16 + l15) * 2048;
    int qbase = lk * 2;

    for (int t = 0; t < SEQ; ++t) {
        const ushort* ah;
        const ushort* al;
        if (t == 0) { ah = h0hi + arow0; al = h0lo + arow0; }
        else {
            size_t off = arowT + (size_t)(t - 1) * HID;
            ah = lstm + off;
            al = hlo + off;
        }

        f32x4 acc0 = {}, acc1 = {};
#pragma unroll 4
        for (int kk = 0; kk < 32; ++kk) {
            int q = (qbase + kk * 64) ^ sw;
            bf16x8 ahi = *(const bf16x8*)(ah + kk * 32);
            bf16x8 alo = *(const bf16x8*)(al + kk * 32);
            bf16x8 bh0 = *(const bf16x8*)(smem + cbase0 + q);
            bf16x8 bh1 = *(const bf16x8*)(smem + cbase1 + q);
            bf16x8 bl0 = *(const bf16x8*)(smem + 65536 + cbase0 + q);
            bf16x8 bl1 = *(const bf16x8*)(smem + 65536 + cbase1 + q);
            acc0 = MFMA(ahi, bh0, acc0);
            acc1 = MFMA(ahi, bh1, acc1);
            acc0 = MFMA(alo, bh0, acc0);
            acc1 = MFMA(alo, bh1, acc1);
            acc0 = MFMA(ahi, bl0, acc0);
            acc1 = MFMA(ahi, bl1, acc1);
        }

        int drow = wave * 16 + (lane >> 4) * 4;
#pragma unroll
        for (int r = 0; r < 4; ++r) {
            gl[(drow + r) * 36 + l15] = acc0[r] + bias0;
            gl[(drow + r) * 36 + 16 + l15] = acc1[r] + bias1;
        }
        __syncthreads();

#pragma unroll
        for (int pp = 0; pp < 2; ++pp) {
            int row = pp ? erow1 : erow0;
            int ul = pp ? eu1 : eu0;
            float4 q4 = *(const float4*)((const char*)gl + row * 144 + ul * 16);
            float xi = q4.x, xf = q4.y, xg = q4.z, xo = q4.w;
            float ig = 1.f / (1.f + __expf(-xi));
            float fg = 1.f / (1.f + __expf(-xf));
            float xgc = fminf(fmaxf(xg, -30.f), 30.f);
            float eg = __expf(-2.f * xgc);
            float gg = (1.f - eg) / (1.f + eg);
            float og = 1.f / (1.f + __expf(-xo));
            float cn = fg * creg[pp] + ig * gg;
            creg[pp] = cn;
            float cc = fminf(fmaxf(cn, -30.f), 30.f);
            float ec = __expf(-2.f * cc);
            float th = (1.f - ec) / (1.f + ec);
            float h = og * th;
            int grow = hf * 128 + row;
            size_t so = (size_t)grow * SH + (size_t)t * HID + ct * 8 + ul;
            ushort hh = f2bf(h);
            ushort hl = f2bf(h - bf2f(hh));
            __hip_atomic_store(&lstm[so], hh, __ATOMIC_RELAXED, __HIP_MEMORY_SCOPE_AGENT);
            __hip_atomic_store(&hlo[so], hl, __ATOMIC_RELAXED, __HIP_MEMORY_SCOPE_AGENT);
        }
        if (t < SEQ - 1) gbar(bar, bid, t);
    }
}

// ---------------------------------------------------------------------------
// persist_pp (MODE B fallback): r8's proven ping-pong sc1 kernel, verbatim.
// ---------------------------------------------------------------------------
__global__ __launch_bounds__(512, 2) void persist_pp(
    const ushort* __restrict__ Whi, const ushort* __restrict__ Wlo,
    const float* __restrict__ biasp, const float* __restrict__ c0,
    ushort* __restrict__ h0hi, ushort* __restrict__ h0lo,
    ushort* __restrict__ h1hi, ushort* __restrict__ h1lo,
    ushort* __restrict__ lstm, unsigned* bar)
{
    extern __shared__ char smem[];
    float* gl = (float*)(smem + 131072);

    int tid = threadIdx.x;
    int bid = blockIdx.x;
    int ct = bid >> 1;
    int hf = bid & 1;
    int wave = tid >> 6, lane = tid & 63;
    int l15 = lane & 15, lk = (lane >> 4) * 8;

    {
        const ushort* srcH = Whi + (size_t)ct * 32768;
        const ushort* srcL = Wlo + (size_t)ct * 32768;
#pragma unroll
        for (int i = 0; i < 8; ++i) {
            int o = (tid + i * 512) * 8;
            int j = o >> 10;
            int kb = (o & 1023) * 2;
            int dst = (j * 2048 + kb) ^ ((j & 7) << 4);
            *(bf16x8*)(smem + dst) = *(const bf16x8*)(srcH + o);
            *(bf16x8*)(smem + 65536 + dst) = *(const bf16x8*)(srcL + o);
        }
    }
    float bias0 = biasp[ct * 32 + l15];
    float bias1 = biasp[ct * 32 + 16 + l15];
    float creg[2];
    int erow0 = tid >> 3, eu0 = tid & 7;
    int erow1 = (tid + 512) >> 3, eu1 = tid & 7;
    creg[0] = c0[(size_t)(hf * 128 + erow0) * HID + ct * 8 + eu0];
    creg[1] = c0[(size_t)(hf * 128 + erow1) * HID + ct * 8 + eu1];
    __syncthreads();

    int r0 = hf * 128 + wave * 16 + l15;
    const size_t arow = (size_t)r0 * HID + lk;
    int sw = (l15 & 7) << 4;
    int cbase0 = l15 * 2048;
    int cbase1 = (16 + l15) * 2048;
    int qbase = lk * 2;

    for (int t = 0; t < SEQ; ++t) {
        const ushort* hH = (t & 1) ? h1hi : h0hi;
        const ushort* hL = (t & 1) ? h1lo : h0lo;
        ushort* oH = (t & 1) ? h0hi : h1hi;
        ushort* oL = (t & 1) ? h0lo : h1lo;

        f32x4 acc0 = {}, acc1 = {};
        const ushort* ah = hH + arow;
        const ushort* al = hL + arow;
#pragma unroll 4
        for (int kk = 0; kk < 32; ++kk) {
            int q = (qbase + kk * 64) ^ sw;
            bf16x8 ahi = ldg_agent16(ah + kk * 32);
            bf16x8 alo = ldg_agent16(al + kk * 32);
            bf16x8 bh0 = *(const bf16x8*)(smem + cbase0 + q);
            bf16x8 bh1 = *(const bf16x8*)(smem + cbase1 + q);
            bf16x8 bl0 = *(const bf16x8*)(smem + 65536 + cbase0 + q);
            bf16x8 bl1 = *(const bf16x8*)(smem + 65536 + cbase1 + q);
            acc0 = MFMA(ahi, bh0, acc0);
            acc1 = MFMA(ahi, bh1, acc1);
            acc0 = MFMA(alo, bh0, acc0);
            acc1 = MFMA(alo, bh1, acc1);
            acc0 = MFMA(ahi, bl0, acc0);
            acc1 = MFMA(ahi, bl1, acc1);
        }

        int drow = wave * 16 + (lane >> 4) * 4;
#pragma unroll
        for (int r = 0; r < 4; ++r) {
            gl[(drow + r) * 36 + l15] = acc0[r] + bias0;
            gl[(drow + r) * 36 + 16 + l15] = acc1[r] + bias1;
        }
        __syncthreads();

        ushort* lst = lstm + (size_t)t * HID;
#pragma unroll
        for (int pp = 0; pp < 2; ++pp) {
            int row = pp ? erow1 : erow0;
            int ul = pp ? eu1 : eu0;
            float4 q4 = *(const float4*)((const char*)gl + row * 144 + ul * 16);
            float xi = q4.x, xf = q4.y, xg = q4.z, xo = q4.w;
            float ig = 1.f / (1.f + __expf(-xi));
            float fg = 1.f / (1.f + __expf(-xf));
            float xgc = fminf(fmaxf(xg, -30.f), 30.f);
            float eg = __expf(-2.f * xgc);
            float gg = (1.f - eg) / (1.f + eg);
            float og = 1.f / (1.f + __expf(-xo));
            float cn = fg * creg[pp] + ig * gg;
            creg[pp] = cn;
            float cc = fminf(fmaxf(cn, -30.f), 30.f);
            float ec = __expf(-2.f * cc);
            float th = (1.f - ec) / (1.f + ec);
            float h = og * th;
            int grow = hf * 128 + row;
            size_t gi = (size_t)grow * HID + ct * 8 + ul;
            ushort hh = f2bf(h);
            ushort hl = f2bf(h - bf2f(hh));
            __hip_atomic_store(&oH[gi], hh, __ATOMIC_RELAXED, __HIP_MEMORY_SCOPE_AGENT);
            __hip_atomic_store(&oL[gi], hl, __ATOMIC_RELAXED, __HIP_MEMORY_SCOPE_AGENT);
            lst[(size_t)grow * SH + ct * 8 + ul] = hh;
        }
        if (t < SEQ - 1) gbar(bar, bid, t);
    }
}

// ---------------------------------------------------------------------------
// step (non-cooperative FALLBACK, proven round-2 path)
// ---------------------------------------------------------------------------
__global__ __launch_bounds__(512) void step_kernel(
    const ushort* __restrict__ hin_hi, const ushort* __restrict__ hin_lo,
    float* __restrict__ c,
    ushort* __restrict__ hout_hi, ushort* __restrict__ hout_lo,
    ushort* __restrict__ lstm_t,
    const ushort* __restrict__ Whi, const ushort* __restrict__ Wlo,
    const float* __restrict__ biasp)
{
    __shared__ float gl[64][65];
    int tid = threadIdx.x;
    int wave = tid >> 6, lane = tid & 63;
    int wm = wave >> 2, wn = wave & 3;
    int ntile = blockIdx.x & 63, mtile = blockIdx.x >> 6;
    int N0 = ntile * 64, b0 = mtile * 64;
    int l15 = lane & 15, lk = (lane >> 4) * 8;

    f32x4 acc0 = {}, acc1 = {};
    int row0 = b0 + wm * 32 + l15;
    int colj = N0 + wn * 16 + l15;

    for (int pass = 0; pass < 3; ++pass) {
        const ushort* Ap = (pass == 1) ? hin_lo : hin_hi;
        const ushort* Bp = (pass == 2) ? Wlo : Whi;
        const ushort* a0p = Ap + (size_t)row0 * HID + lk;
        const ushort* a1p = a0p + 16 * HID;
        const ushort* bp = Bp + (size_t)colj * HID + lk;
#pragma unroll 8
        for (int k0 = 0; k0 < 32; ++k0) {
            bf16x8 a0 = *(const bf16x8*)(a0p + k0 * 32);
            bf16x8 a1 = *(const bf16x8*)(a1p + k0 * 32);
            bf16x8 bb = *(const bf16x8*)(bp + k0 * 32);
            acc0 = MFMA(a0, bb, acc0);
            acc1 = MFMA(a1, bb, acc1);
        }
    }
    int cl = wn * 16 + l15;
    int rbase = wm * 32 + (lane >> 4) * 4;
#pragma unroll
    for (int r = 0; r < 4; ++r) {
        gl[rbase + r][cl] = acc0[r];
        gl[rbase + 16 + r][cl] = acc1[r];
    }
    __syncthreads();
#pragma unroll
    for (int pp = 0; pp < 2; ++pp) {
        int p = tid + 512 * pp;
        int bl = p >> 4, ul = p & 15;
        int jb = N0 + ul * 4;
        float xi = gl[bl][ul * 4 + 0] + biasp[jb + 0];
        float xf = gl[bl][ul * 4 + 1] + biasp[jb + 1];
        float xg = gl[bl][ul * 4 + 2] + biasp[jb + 2];
        float xo = gl[bl][ul * 4 + 3] + biasp[jb + 3];
        float ig = 1.f / (1.f + __expf(-xi));
        float fg = 1.f / (1.f + __expf(-xf));
        float xgc = fminf(fmaxf(xg, -30.f), 30.f);
        float eg = __expf(-2.f * xgc);
        float gg = (1.f - eg) / (1.f + eg);
        float og = 1.f / (1.f + __expf(-xo));
        int gidx = (b0 + bl) * HID + (N0 >> 2) + ul;
        float cn = fg * c[gidx] + ig * gg;
        float cc = fminf(fmaxf(cn, -30.f), 30.f);
        float ec = __expf(-2.f * cc);
        float th = (1.f - ec) / (1.f + ec);
        float h = og * th;
        c[gidx] = cn;
        ushort hh = f2bf(h);
        hout_hi[gidx] = hh;
        hout_lo[gidx] = f2bf(h - bf2f(hh));
        lstm_t[(size_t)(b0 + bl) * SH + (N0 >> 2) + ul] = hh;
    }
}

// ---------------------------------------------------------------------------
// final: predictions[38400,128] = lstm_bf16 @ WoutB^T + b_out
// ---------------------------------------------------------------------------
__global__ __launch_bounds__(512) void final_kernel(
    const ushort* __restrict__ lstm, const ushort* __restrict__ WoutB,
    const float* __restrict__ b_out, float* __restrict__ out)
{
    int tid = threadIdx.x;
    int wave = tid >> 6, lane = tid & 63;
    int wr = wave >> 2, wc = wave & 3;
    int m0 = blockIdx.x * 32;
    int l15 = lane & 15, lk = (lane >> 4) * 8;
    int r0 = m0 + wr * 16 + l15;
    int j0 = wc * 32 + l15;
    f32x4 acc0 = {}, acc1 = {};
    const ushort* ap = lstm + (size_t)r0 * HID + lk;
    const ushort* bp0 = WoutB + (size_t)j0 * HID + lk;
    const ushort* bp1 = bp0 + (size_t)16 * HID;
#pragma unroll 8
    for (int k0 = 0; k0 < 32; ++k0) {
        bf16x8 a = *(const bf16x8*)(ap + k0 * 32);
        bf16x8 b0 = *(const bf16x8*)(bp0 + k0 * 32);
        bf16x8 b1 = *(const bf16x8*)(bp1 + k0 * 32);
        acc0 = MFMA(a, b0, acc0);
        acc1 = MFMA(a, b1, acc1);
    }
#pragma unroll
    for (int r = 0; r < 4; ++r) {
        int rA = m0 + wr * 16 + (lane >> 4) * 4 + r;
        int c0 = wc * 32 + l15, c1 = c0 + 16;
        out[(size_t)rA * OUTSZ + c0] = acc0[r] + b_out[c0];
        out[(size_t)rA * OUTSZ + c1] = acc1[r] + b_out[c1];
    }
}

// ---------------------------------------------------------------------------
extern "C" void kernel_launch(void* const* d_in, const int* in_sizes, int n_in,
                              void* d_out, int out_size, void* d_ws, size_t ws_size,
                              hipStream_t stream)
{
    const float* init_input = (const float*)d_in[0];
    const float* W_in_h = (const float*)d_in[1];
    const float* b_in_h = (const float*)d_in[2];
    const float* W_in_c = (const float*)d_in[3];
    const float* b_in_c = (const float*)d_in[4];
    const float* W_hh = (const float*)d_in[5];
    const float* b_ih = (const float*)d_in[6];
    const float* b_hh = (const float*)d_in[7];
    const float* W_out = (const float*)d_in[8];
    const float* b_out = (const float*)d_in[9];
    float* out = (float*)d_out;

    char* ws = (char*)d_ws;
    ushort* Whi = (ushort*)(ws);                    // 8 MB
    ushort* Wlo = (ushort*)(ws + 8388608);          // 8 MB
    ushort* WoutB = (ushort*)(ws + 16777216);       // 256 KB
    float* biasp = (float*)(ws + 17039360);         // 16 KB
    ushort* hA_hi = (ushort*)(ws + 17055744);       // 512 KB
    ushort* hA_lo = (ushort*)(ws + 17580032);       // 512 KB
    ushort* hB_hi = (ushort*)(ws + 18104320);       // 512 KB
    ushort* hB_lo = (ushort*)(ws + 18628608);       // 512 KB
    float* cbuf = (float*)(ws + 19152896);          // 1 MB
    ushort* lstm = (ushort*)(ws + 20201472);        // 78.6 MB -> ends 98844672
    ushort* hlo  = (ushort*)(ws + 98844672);        // 78.6 MB -> ends 177487872 (mode A)
    unsigned* barA = (unsigned*)(ws + 177487872);   // 4 KB
    unsigned* barB = (unsigned*)(ws + 98844672);    // 4 KB (mode B, overlays hlo)

    hipLaunchKernelGGL(prep_kernel, dim3(4224), dim3(256), 0, stream,
                       W_hh, b_ih, b_hh, W_out, Whi, Wlo, WoutB, biasp);
    hipLaunchKernelGGL(init_kernel, dim3(256), dim3(256), 0, stream,
                       init_input, W_in_h, b_in_h, W_in_c, b_in_c,
                       hA_hi, hA_lo, cbuf);

    bool launched = false;
    if (ws_size >= (size_t)177487872 + 4096) {
        // MODE A: write-once transport, plain cached reads
        hipMemsetAsync(barA, 0, 4096, stream);
        hipFuncSetAttribute((const void*)persist_seq,
                            hipFuncAttributeMaxDynamicSharedMemorySize, PERSIST_LDS);
        const ushort* a0 = Whi; const ushort* a1 = Wlo;
        const float* a2 = biasp; const float* a3 = cbuf;
        const ushort* a4 = hA_hi; const ushort* a5 = hA_lo;
        ushort* a6 = lstm; ushort* a7 = hlo; unsigned* a8 = barA;
        void* kargs[] = {(void*)&a0, (void*)&a1, (void*)&a2, (void*)&a3,
                         (void*)&a4, (void*)&a5, (void*)&a6, (void*)&a7,
                         (void*)&a8};
        launched = (hipLaunchCooperativeKernel((void*)persist_seq,
                                               dim3(256), dim3(512), kargs,
                                               PERSIST_LDS, stream) == hipSuccess);
    } else if (ws_size >= (size_t)98844672 + 4096) {
        // MODE B: r8 proven ping-pong sc1 path
        hipMemsetAsync(barB, 0, 4096, stream);
        hipFuncSetAttribute((const void*)persist_pp,
                            hipFuncAttributeMaxDynamicSharedMemorySize, PERSIST_LDS);
        const ushort* a0 = Whi; const ushort* a1 = Wlo;
        const float* a2 = biasp; const float* a3 = cbuf;
        ushort* a4 = hA_hi; ushort* a5 = hA_lo;
        ushort* a6 = hB_hi; ushort* a7 = hB_lo;
        ushort* a8 = lstm; unsigned* a9 = barB;
        void* kargs[] = {(void*)&a0, (void*)&a1, (void*)&a2, (void*)&a3,
                         (void*)&a4, (void*)&a5, (void*)&a6, (void*)&a7,
                         (void*)&a8, (void*)&a9};
        launched = (hipLaunchCooperativeKernel((void*)persist_pp,
                                               dim3(256), dim3(512), kargs,
                                               PERSIST_LDS, stream) == hipSuccess);
    }
    if (!launched) {
        for (int t = 0; t < SEQ; ++t) {
            const ushort* ih = (t & 1) ? hB_hi : hA_hi;
            const ushort* il = (t & 1) ? hB_lo : hA_lo;
            ushort* oh = (t & 1) ? hA_hi : hB_hi;
            ushort* ol = (t & 1) ? hA_lo : hB_lo;
            hipLaunchKernelGGL(step_kernel, dim3(256), dim3(512), 0, stream,
                               ih, il, cbuf, oh, ol, lstm + (size_t)t * HID,
                               Whi, Wlo, biasp);
        }
    }
    hipLaunchKernelGGL(final_kernel, dim3(1200), dim3(512), 0, stream,
                       lstm, WoutB, b_out, out);
}